// Round 2
// baseline (302.138 us; speedup 1.0000x reference)
//
#include <hip/hip_runtime.h>

// TransformerBlock on MI355X (gfx950).
// v11: attention occupancy fix. 512-thread blocks, 8 waves: waves 0-3 handle
// keys 0-1023, waves 4-7 keys 1024-2047 (in-block split-K). 64-key tiles
// (16KB K+V image), per-group double buffer -> LDS 64KB, 2 blocks/CU,
// 16 waves/CU (4/SIMD, was 2/SIMD). Partials combined in-block via LDS.
// Producer (gemm_in) writes 64-key-granular pre-swizzled tile images.
// setprio(1) around MFMA clusters. Weight casts merged into one launch.

typedef __bf16 bf16;
typedef bf16 bf16x8 __attribute__((ext_vector_type(8)));
typedef bf16 bf16x4 __attribute__((ext_vector_type(4)));
typedef float f32x4 __attribute__((ext_vector_type(4)));
typedef float f32x16 __attribute__((ext_vector_type(16)));

#define EMB 1024
#define SEQ 2048
#define NTOK 4096
#define NH 16
#define HD 64

__device__ __forceinline__ f32x4 mfma16(bf16x8 a, bf16x8 b, f32x4 c) {
  return __builtin_amdgcn_mfma_f32_16x16x32_bf16(a, b, c, 0, 0, 0);
}
__device__ __forceinline__ f32x16 mfma32(bf16x8 a, bf16x8 b, f32x16 c) {
  return __builtin_amdgcn_mfma_f32_32x32x16_bf16(a, b, c, 0, 0, 0);
}

__device__ __forceinline__ void gll16(const void* g, void* l) {
  __builtin_amdgcn_global_load_lds(
      (const __attribute__((address_space(1))) void*)g,
      (__attribute__((address_space(3))) void*)l, 16, 0, 0);
}

__device__ __forceinline__ unsigned pk2(float a, float b) {
  union { bf16 h[2]; unsigned u; } t;
  t.h[0] = (bf16)a; t.h[1] = (bf16)b;
  return t.u;
}

// ---------------- elementwise prep ----------------

__global__ __launch_bounds__(256) void rope_cast(
    const float* __restrict__ x, bf16* __restrict__ xb, bf16* __restrict__ qr) {
  int idx = blockIdx.x * 256 + threadIdx.x;   // 0 .. NTOK*512
  int row = idx >> 9;
  int i = idx & 511;
  int h = i >> 5, d2 = i & 31;
  int pos = row & (SEQ - 1);
  int c0 = h * HD + d2;
  size_t base = (size_t)row * EMB;
  float x0 = x[base + c0], x1 = x[base + c0 + 32];
  float invf = exp2f(-(float)d2 * 0.4152410118609203f);
  float ang = (float)pos * invf;
  float sn, cs;
  sincosf(ang, &sn, &cs);
  qr[base + c0] = (bf16)(x0 * cs - x1 * sn);
  qr[base + c0 + 32] = (bf16)(x1 * cs + x0 * sn);
  xb[base + c0] = (bf16)x0;
  xb[base + c0 + 32] = (bf16)x1;
}

// all three weight casts in one launch
__global__ __launch_bounds__(256) void cast_all(
    const float* __restrict__ w0, const float* __restrict__ w1,
    const float* __restrict__ w2, bf16* __restrict__ o0,
    bf16* __restrict__ o1, bf16* __restrict__ o2) {
  int i = (blockIdx.x * 256 + threadIdx.x) * 4;
  const float* s; bf16* d; int off;
  if (i < 3 * 1024 * 1024) { s = w0; d = o0; off = i; }
  else if (i < 4 * 1024 * 1024) { s = w1; d = o1; off = i - 3 * 1024 * 1024; }
  else { s = w2; d = o2; off = i - 4 * 1024 * 1024; }
  float4 f = *(const float4*)(s + off);
  d[off] = (bf16)f.x; d[off + 1] = (bf16)f.y;
  d[off + 2] = (bf16)f.z; d[off + 3] = (bf16)f.w;
}

// ---------------- fused in-proj GEMM ----------------
// Outputs: qb[token][1024] pre-scaled by 0.125; kv images per (b,h): 32 tiles
// of 64 keys, each {K 4096 elem | V 4096 elem} in the exact attention LDS
// layout. K pre-scaled by log2(e).
__global__ __launch_bounds__(256) void gemm_in(
    const bf16* __restrict__ Aq, const bf16* __restrict__ Ax,
    const bf16* __restrict__ W, const float* __restrict__ bias,
    bf16* __restrict__ qb, bf16* __restrict__ kv) {
  __shared__ bf16 As[128 * 32];
  __shared__ bf16 Bs[128 * 32];
  const int tid = threadIdx.x, lane = tid & 63, wave = tid >> 6;
  const int quad = lane >> 4, l16 = lane & 15;
  const int m0 = blockIdx.y * 128, n0 = blockIdx.x * 128;
  const bf16* A = (n0 < 2048) ? Aq : Ax;
  const int K = 1024;
  const int wm = (wave >> 1) * 64, wn = (wave & 1) * 64;
  const int srow = wave * 32 + (lane >> 2);
  const int scol = (lane & 3) * 8;
  f32x4 acc[4][4] = {};
  for (int k0 = 0; k0 < K; k0 += 32) {
    __syncthreads();
    gll16(A + (size_t)(m0 + srow) * K + k0 + scol, As + wave * 1024);
    gll16(A + (size_t)(m0 + srow + 16) * K + k0 + scol, As + wave * 1024 + 512);
    gll16(W + (size_t)(n0 + srow) * K + k0 + scol, Bs + wave * 1024);
    gll16(W + (size_t)(n0 + srow + 16) * K + k0 + scol, Bs + wave * 1024 + 512);
    __syncthreads();
    bf16x8 af[4], bw[4];
#pragma unroll
    for (int t = 0; t < 4; ++t) {
      af[t] = *(const bf16x8*)(As + (wm + t * 16 + l16) * 32 + quad * 8);
      bw[t] = *(const bf16x8*)(Bs + (wn + t * 16 + l16) * 32 + quad * 8);
    }
#pragma unroll
    for (int mt = 0; mt < 4; ++mt)
#pragma unroll
      for (int nt = 0; nt < 4; ++nt)
        acc[mt][nt] = mfma16(af[mt], bw[nt], acc[mt][nt]);
  }
  if (n0 < 1024) {
    // Q: scale 1/8 (exact in bf16)
#pragma unroll
    for (int mt = 0; mt < 4; ++mt)
      for (int nt = 0; nt < 4; ++nt) {
        const int n = n0 + wn + nt * 16 + l16;
        const float bv = bias[n];
#pragma unroll
        for (int r = 0; r < 4; ++r) {
          const int m = m0 + wm + mt * 16 + quad * 4 + r;
          qb[(size_t)m * 1024 + n] = (bf16)((acc[mt][nt][r] + bv) * 0.125f);
        }
      }
  } else if (n0 < 2048) {
    // K: scale log2(e), write into swizzled 64-key tile image
#pragma unroll
    for (int mt = 0; mt < 4; ++mt)
      for (int nt = 0; nt < 4; ++nt) {
        const int n = n0 + wn + nt * 16 + l16;
        const float bv = bias[n];
        const int kd = n - 1024, hh = kd >> 6, d = kd & 63;
        const int dc = d >> 3, dl = d & 7;
#pragma unroll
        for (int r = 0; r < 4; ++r) {
          const int m = m0 + wm + mt * 16 + quad * 4 + r;
          const int bb = m >> 11, s = m & 2047;
          const int t = s >> 6, kr = s & 63;
          const size_t base = ((size_t)((bb * 16 + hh) * 32 + t)) * 8192;
          kv[base + kr * 64 + ((dc ^ (kr & 7)) << 3) + dl] =
              (bf16)((acc[mt][nt][r] + bv) * 1.4426950408889634f);
        }
      }
  } else {
    // V: permuted+swizzled 64-key tile image, 4 tokens per bf16x4
#pragma unroll
    for (int mt = 0; mt < 4; ++mt)
      for (int nt = 0; nt < 4; ++nt) {
        const int n = n0 + wn + nt * 16 + l16;
        const float bv = bias[n];
        const int vd = n - 2048, hh = vd >> 6, d = vd & 63;
        const int m = m0 + wm + mt * 16 + quad * 4;
        const int bb = m >> 11, s = m & 2047;
        const int t = s >> 6, kt = s & 63;
        const int g = kt >> 4, w = kt & 15;
        const int c = 2 * g + ((w >> 2) & 1);
        const int slot = (w & 8) ? 4 : 0;
        const size_t base = ((size_t)((bb * 16 + hh) * 32 + t)) * 8192 + 4096;
        bf16x4 pkv;
#pragma unroll
        for (int r = 0; r < 4; ++r) pkv[r] = (bf16)(acc[mt][nt][r] + bv);
        *(bf16x4*)(kv + base + d * 64 + ((c ^ (d & 7)) << 3) + slot) = pkv;
      }
  }
}

// ---------------- GEMM 128x128: C = A @ W^T + bias ----------------
__global__ __launch_bounds__(256) void gemm_bt(
    const bf16* __restrict__ A, const bf16* __restrict__ W,
    const float* __restrict__ bias,
    float* __restrict__ outF, bf16* __restrict__ outB,
    int M, int N, int K) {
  __shared__ bf16 As[128 * 32];
  __shared__ bf16 Bs[128 * 32];
  const int tid = threadIdx.x, lane = tid & 63, wave = tid >> 6;
  const int quad = lane >> 4, l16 = lane & 15;
  const int m0 = blockIdx.y * 128, n0 = blockIdx.x * 128;
  const int wm = (wave >> 1) * 64, wn = (wave & 1) * 64;
  const int srow = wave * 32 + (lane >> 2);
  const int scol = (lane & 3) * 8;
  f32x4 acc[4][4] = {};
  for (int k0 = 0; k0 < K; k0 += 32) {
    __syncthreads();
    gll16(A + (size_t)(m0 + srow) * K + k0 + scol, As + wave * 1024);
    gll16(A + (size_t)(m0 + srow + 16) * K + k0 + scol, As + wave * 1024 + 512);
    gll16(W + (size_t)(n0 + srow) * K + k0 + scol, Bs + wave * 1024);
    gll16(W + (size_t)(n0 + srow + 16) * K + k0 + scol, Bs + wave * 1024 + 512);
    __syncthreads();
    bf16x8 af[4], bw[4];
#pragma unroll
    for (int t = 0; t < 4; ++t) {
      af[t] = *(const bf16x8*)(As + (wm + t * 16 + l16) * 32 + quad * 8);
      bw[t] = *(const bf16x8*)(Bs + (wn + t * 16 + l16) * 32 + quad * 8);
    }
#pragma unroll
    for (int mt = 0; mt < 4; ++mt)
#pragma unroll
      for (int nt = 0; nt < 4; ++nt)
        acc[mt][nt] = mfma16(af[mt], bw[nt], acc[mt][nt]);
  }
#pragma unroll
  for (int mt = 0; mt < 4; ++mt)
    for (int nt = 0; nt < 4; ++nt) {
      const int n = n0 + wn + nt * 16 + l16;
      const float bv = bias ? bias[n] : 0.0f;
#pragma unroll
      for (int r = 0; r < 4; ++r) {
        const int m = m0 + wm + mt * 16 + quad * 4 + r;
        const float v = acc[mt][nt][r] + bv;
        if (outF) outF[(size_t)m * N + n] = v;
        if (outB) outB[(size_t)m * N + n] = (bf16)v;
      }
    }
}

// ---------------- GEMM 128x64 tiles ----------------
__global__ __launch_bounds__(256) void gemm_bt64(
    const bf16* __restrict__ A, const bf16* __restrict__ W,
    const float* __restrict__ bias, float* __restrict__ outF,
    int M, int N, int K) {
  __shared__ bf16 As[128 * 32];
  __shared__ bf16 Bs[64 * 32];
  const int tid = threadIdx.x, lane = tid & 63, wave = tid >> 6;
  const int quad = lane >> 4, l16 = lane & 15;
  const int m0 = blockIdx.y * 128, n0 = blockIdx.x * 64;
  const int wm = (wave >> 1) * 64, wn = (wave & 1) * 32;
  const int srow = wave * 32 + (lane >> 2);
  const int srowB = wave * 16 + (lane >> 2);
  const int scol = (lane & 3) * 8;
  f32x4 acc[4][2] = {};
  for (int k0 = 0; k0 < K; k0 += 32) {
    __syncthreads();
    gll16(A + (size_t)(m0 + srow) * K + k0 + scol, As + wave * 1024);
    gll16(A + (size_t)(m0 + srow + 16) * K + k0 + scol, As + wave * 1024 + 512);
    gll16(W + (size_t)(n0 + srowB) * K + k0 + scol, Bs + wave * 512);
    __syncthreads();
    bf16x8 af[4], bw[2];
#pragma unroll
    for (int t = 0; t < 4; ++t)
      af[t] = *(const bf16x8*)(As + (wm + t * 16 + l16) * 32 + quad * 8);
#pragma unroll
    for (int t = 0; t < 2; ++t)
      bw[t] = *(const bf16x8*)(Bs + (wn + t * 16 + l16) * 32 + quad * 8);
#pragma unroll
    for (int mt = 0; mt < 4; ++mt)
#pragma unroll
      for (int nt = 0; nt < 2; ++nt)
        acc[mt][nt] = mfma16(af[mt], bw[nt], acc[mt][nt]);
  }
#pragma unroll
  for (int mt = 0; mt < 4; ++mt)
    for (int nt = 0; nt < 2; ++nt) {
      const int n = n0 + wn + nt * 16 + l16;
      const float bv = bias[n];
#pragma unroll
      for (int r = 0; r < 4; ++r) {
        const int m = m0 + wm + mt * 16 + quad * 4 + r;
        outF[(size_t)m * N + n] = acc[mt][nt][r] + bv;
      }
    }
}

// ---------------- flash attention v11: in-block split-K ----------------
// 512 blocks x 512 threads. Waves 0-3: keys 0-1023; waves 4-7: keys 1024-2047.
// 64-key tiles, per-group double buffer (LDS 64KB total), partial O/L combined
// in-block via LDS at the end. 16 waves/CU.
__global__ __launch_bounds__(512, 4) void attn11(
    const bf16* __restrict__ Q, const bf16* __restrict__ KV,
    bf16* __restrict__ ctx) {
  __shared__ __align__(16) bf16 kvb[2][2][8192];  // [group][buf][K 4096|V 4096]
  const int tid = threadIdx.x, lane = tid & 63, wave = tid >> 6;
  const int grp = wave >> 2, lw = wave & 3;
  const int hi = lane >> 5, l31 = lane & 31, l7 = lane & 7;
  const int bid = blockIdx.x;
  const int hb = (bid & 7) * 4 + ((bid >> 3) & 3);
  const int qt = bid >> 5;              // 0..15
  const int h = hb & 15, b = hb >> 4;

  // Q B-frags (lane owns col q = l31; k=d=tt*16+hi*8+j), producer-scaled 1/8
  bf16x8 qf[4];
  {
    const int qrow = qt * 128 + lw * 32 + l31;
    const bf16* qp = Q + (size_t)(b * SEQ + qrow) * 1024 + h * HD + hi * 8;
#pragma unroll
    for (int t = 0; t < 4; ++t) qf[t] = *(const bf16x8*)(qp + t * 16);
  }
  // staging: group's tile stream (16 tiles of 8192 elems), 4 x gll16/thread
  const int soff = lw * 2048 + lane * 8;
  const bf16* kvg = KV + ((size_t)((b * NH + h) * 32 + grp * 16)) * 8192 + soff;
  bf16* myb[2] = {&kvb[grp][0][0], &kvb[grp][1][0]};
#pragma unroll
  for (int i = 0; i < 4; ++i)           // stage tile 0 into buf 0
    gll16(kvg + i * 512, myb[0] + soff + i * 512);

  f32x16 o0 = {}, o1 = {}, lacc = {};
  const f32x16 zf = {};
  const bf16 onec = (bf16)1.0f;
  const bf16x8 onef = {onec, onec, onec, onec, onec, onec, onec, onec};

  for (int t = 0; t < 16; ++t) {
    __syncthreads();                    // buf[t&1] ready for all waves
    if (t + 1 < 16) {                   // prefetch next tile into other buffer
      const bf16* src = kvg + (size_t)(t + 1) * 8192;
      bf16* dst = myb[(t + 1) & 1] + soff;
#pragma unroll
      for (int i = 0; i < 4; ++i) gll16(src + i * 512, dst + i * 512);
    }
    const bf16* ks = myb[t & 1];
    const bf16* vs = ks + 4096;
    f32x16 s0, s1;
    __builtin_amdgcn_s_setprio(1);
    {
      const int swc = (hi ^ l7) * 8;
      bf16x8 k0 = *(const bf16x8*)(ks + l31 * 64 + swc);
      bf16x8 k1 = *(const bf16x8*)(ks + (32 + l31) * 64 + swc);
      s0 = mfma32(k0, qf[0], zf);       // zero-C: no per-tile re-zero movs
      s1 = mfma32(k1, qf[0], zf);
    }
#pragma unroll
    for (int tt = 1; tt < 4; ++tt) {
      const int swc = ((tt * 2 + hi) ^ l7) * 8;
      bf16x8 k0 = *(const bf16x8*)(ks + l31 * 64 + swc);
      bf16x8 k1 = *(const bf16x8*)(ks + (32 + l31) * 64 + swc);
      s0 = mfma32(k0, qf[tt], s0);
      s1 = mfma32(k1, qf[tt], s1);
    }
    __builtin_amdgcn_s_setprio(0);
    unsigned u[16];
#pragma unroll
    for (int g = 0; g < 8; ++g) {
      const int base = (g & 3) * 4;
      float e0, e1, e2, e3;
      if (g < 4) {
        e0 = __builtin_amdgcn_exp2f(s0[base]);
        e1 = __builtin_amdgcn_exp2f(s0[base + 1]);
        e2 = __builtin_amdgcn_exp2f(s0[base + 2]);
        e3 = __builtin_amdgcn_exp2f(s0[base + 3]);
      } else {
        e0 = __builtin_amdgcn_exp2f(s1[base]);
        e1 = __builtin_amdgcn_exp2f(s1[base + 1]);
        e2 = __builtin_amdgcn_exp2f(s1[base + 2]);
        e3 = __builtin_amdgcn_exp2f(s1[base + 3]);
      }
      u[g * 2] = pk2(e0, e1);
      u[g * 2 + 1] = pk2(e2, e3);
    }
    // PV (+ ones-MFMA row-sum): chunk = (2kk + hi) ^ l7
    __builtin_amdgcn_s_setprio(1);
#pragma unroll
    for (int kk = 0; kk < 4; ++kk) {
      union { unsigned w[4]; bf16x8 v; } fw;
      fw.w[0] = u[4 * kk]; fw.w[1] = u[4 * kk + 1];
      fw.w[2] = u[4 * kk + 2]; fw.w[3] = u[4 * kk + 3];
      const int c16 = (2 * kk + hi) ^ l7;
      bf16x8 v0 = *(const bf16x8*)(vs + l31 * 64 + c16 * 8);
      bf16x8 v1 = *(const bf16x8*)(vs + (32 + l31) * 64 + c16 * 8);
      lacc = mfma32(fw.v, onef, lacc);  // denom, same D-row map as o0/o1
      o0 = mfma32(fw.v, v0, o0);
      o1 = mfma32(fw.v, v1, o1);
    }
    __builtin_amdgcn_s_setprio(0);
  }
  // in-block split-K combine: group 1 parks partials in LDS (reuses kvb)
  __syncthreads();
  float* fred = (float*)&kvb[0][0][0];  // 4 waves x 64 lanes x 49 floats
  if (grp == 1) {
    float* p = fred + (size_t)(lw * 64 + lane) * 49;
#pragma unroll
    for (int r = 0; r < 16; ++r) {
      p[r] = o0[r]; p[16 + r] = o1[r]; p[32 + r] = lacc[r];
    }
  }
  __syncthreads();
  if (grp == 0) {
    const float* p = fred + (size_t)(lw * 64 + lane) * 49;
#pragma unroll
    for (int r = 0; r < 16; ++r) {
      const int qloc = (r & 3) + 8 * (r >> 2) + 4 * hi;
      const float inv = 1.0f / (lacc[r] + p[32 + r]);
      const int qrow = qt * 128 + lw * 32 + qloc;
      bf16* cp = ctx + (size_t)(b * SEQ + qrow) * EMB + h * HD;
      cp[l31] = (bf16)((o0[r] + p[r]) * inv);
      cp[32 + l31] = (bf16)((o1[r] + p[16 + r]) * inv);
    }
  }
}

// ---------------- residual + LayerNorm ----------------
__global__ __launch_bounds__(256) void ln1_k(
    const float* __restrict__ x, const float* __restrict__ ao,
    const float* __restrict__ g, const float* __restrict__ bta,
    float* __restrict__ hF, bf16* __restrict__ hB) {
  int row = blockIdx.x, tid = threadIdx.x;
  const float* xr = x + (size_t)row * EMB;
  const float* ar = ao + (size_t)row * EMB;
  float v[4], s = 0.0f, s2 = 0.0f;
#pragma unroll
  for (int i = 0; i < 4; ++i) {
    float t = xr[tid + i * 256] + ar[tid + i * 256];
    v[i] = t; s += t; s2 += t * t;
  }
#pragma unroll
  for (int off = 1; off < 64; off <<= 1) {
    s += __shfl_xor(s, off, 64);
    s2 += __shfl_xor(s2, off, 64);
  }
  __shared__ float red[8];
  int wave = tid >> 6, lane = tid & 63;
  if (lane == 0) { red[wave] = s; red[4 + wave] = s2; }
  __syncthreads();
  s = red[0] + red[1] + red[2] + red[3];
  s2 = red[4] + red[5] + red[6] + red[7];
  float mean = s * (1.0f / EMB);
  float var = s2 * (1.0f / EMB) - mean * mean;
  float inv = rsqrtf(var + 1e-5f);
#pragma unroll
  for (int i = 0; i < 4; ++i) {
    int c = tid + i * 256;
    float t = (v[i] - mean) * inv * g[c] + bta[c];
    hF[(size_t)row * EMB + c] = t;
    hB[(size_t)row * EMB + c] = (bf16)t;
  }
}

__global__ __launch_bounds__(256) void geglu_ln2(
    const float* __restrict__ h, const bf16* __restrict__ proj,
    const float* __restrict__ g, const float* __restrict__ bta,
    float* __restrict__ out) {
  int row = blockIdx.x, tid = threadIdx.x;
  const float* hr = h + (size_t)row * EMB;
  const bf16* pr = proj + (size_t)row * 2048;
  float v[4], s = 0.0f, s2 = 0.0f;
#pragma unroll
  for (int i = 0; i < 4; ++i) {
    int c = tid + i * 256;
    float val = (float)pr[c];
    float gate = (float)pr[1024 + c];
    float ge = 0.5f * gate * (1.0f + erff(gate * 0.70710678f));
    float t = hr[c] + val * ge;
    v[i] = t; s += t; s2 += t * t;
  }
#pragma unroll
  for (int off = 1; off < 64; off <<= 1) {
    s += __shfl_xor(s, off, 64);
    s2 += __shfl_xor(s2, off, 64);
  }
  __shared__ float red[8];
  int wave = tid >> 6, lane = tid & 63;
  if (lane == 0) { red[wave] = s; red[4 + wave] = s2; }
  __syncthreads();
  s = red[0] + red[1] + red[2] + red[3];
  s2 = red[4] + red[5] + red[6] + red[7];
  float mean = s * (1.0f / EMB);
  float var = s2 * (1.0f / EMB) - mean * mean;
  float inv = rsqrtf(var + 1e-5f);
#pragma unroll
  for (int i = 0; i < 4; ++i) {
    int c = tid + i * 256;
    out[(size_t)row * EMB + c] = (v[i] - mean) * inv * g[c] + bta[c];
  }
}

extern "C" void kernel_launch(void* const* d_in, const int* in_sizes, int n_in,
                              void* d_out, int out_size, void* d_ws, size_t ws_size,
                              hipStream_t stream) {
  const float* x = (const float*)d_in[0];
  const float* inW = (const float*)d_in[1];
  const float* inB = (const float*)d_in[2];
  const float* outW = (const float*)d_in[3];
  const float* opB = (const float*)d_in[4];
  const float* ggW = (const float*)d_in[5];
  const float* ggB = (const float*)d_in[6];
  const float* g1 = (const float*)d_in[7];
  const float* b1 = (const float*)d_in[8];
  const float* g2 = (const float*)d_in[9];
  const float* b2 = (const float*)d_in[10];
  float* out = (float*)d_out;
  char* ws = (char*)d_ws;
  const size_t MB = 1ull << 20;
  bf16* xb = (bf16*)(ws);              // 8 MB, dead after gemm_in
  bf16* hB = (bf16*)(ws);              // overlays xb (ln1 out)
  bf16* qr = (bf16*)(ws + 8 * MB);     // 8 MB, dead after gemm_in
  bf16* ctx = (bf16*)(ws + 8 * MB);    // overlays qr (attn output)
  bf16* wI = (bf16*)(ws + 16 * MB);    // 6 MB
  bf16* wO = (bf16*)(ws + 22 * MB);    // 2 MB
  bf16* wG = (bf16*)(ws + 24 * MB);    // 4 MB
  bf16* qb = (bf16*)(ws + 28 * MB);    // 8 MB, dead after attn
  bf16* kv = (bf16*)(ws + 36 * MB);    // 16 MB tile images, dead after attn
  bf16* projB = (bf16*)(ws + 28 * MB); // overlays qb+kv (GeGLU proj)
  float* ao = (float*)(ws + 52 * MB);  // 16 MB f32

  rope_cast<<<NTOK * 512 / 256, 256, 0, stream>>>(x, xb, qr);
  cast_all<<<6144, 256, 0, stream>>>(inW, outW, ggW, wI, wO, wG);
  gemm_in<<<dim3(24, 32), 256, 0, stream>>>(qr, xb, wI, inB, qb, kv);
  attn11<<<512, 512, 0, stream>>>(qb, kv, ctx);
  gemm_bt64<<<dim3(16, 32), 256, 0, stream>>>(ctx, wO, opB, ao,
                                              NTOK, 1024, 1024);
  ln1_k<<<NTOK, 256, 0, stream>>>(x, ao, g1, b1, ao, hB);
  gemm_bt<<<dim3(16, 32), 256, 0, stream>>>(hB, wG, ggB, nullptr, projB,
                                            NTOK, 2048, 1024);
  geglu_ln2<<<NTOK, 256, 0, stream>>>(ao, projB, g2, b2, out);
}

// Round 3
// 278.237 us; speedup vs baseline: 1.0859x; 1.0859x over previous
//
#include <hip/hip_runtime.h>

// TransformerBlock on MI355X (gfx950).
// v12: v11 split-K attention with the register diet that makes it fit.
// v11 spilled (VGPR split 64/64 at the 128-reg budget of launch_bounds(512,4):
// WRITE_SIZE 31.7MB vs 8MB of real output). v12 drops the ones-MFMA lacc
// denominator (16 accum regs) in favor of VALU lpart + shfl_xor(32) + LDS
// combine (v9-proven pattern), freeing the file: persistent = o0,o1(32 AGPR)
// + qf(16). Structure unchanged: 512-thread blocks, waves 0-3 keys 0-1023,
// waves 4-7 keys 1024-2047, 64-key pre-swizzled tile images staged via
// global_load_lds, double-buffered per group (64KB LDS, 2 blocks/CU,
// 16 waves/CU), in-block partial combine via LDS.

typedef __bf16 bf16;
typedef bf16 bf16x8 __attribute__((ext_vector_type(8)));
typedef bf16 bf16x4 __attribute__((ext_vector_type(4)));
typedef float f32x4 __attribute__((ext_vector_type(4)));
typedef float f32x16 __attribute__((ext_vector_type(16)));

#define EMB 1024
#define SEQ 2048
#define NTOK 4096
#define NH 16
#define HD 64

__device__ __forceinline__ f32x4 mfma16(bf16x8 a, bf16x8 b, f32x4 c) {
  return __builtin_amdgcn_mfma_f32_16x16x32_bf16(a, b, c, 0, 0, 0);
}
__device__ __forceinline__ f32x16 mfma32(bf16x8 a, bf16x8 b, f32x16 c) {
  return __builtin_amdgcn_mfma_f32_32x32x16_bf16(a, b, c, 0, 0, 0);
}

__device__ __forceinline__ void gll16(const void* g, void* l) {
  __builtin_amdgcn_global_load_lds(
      (const __attribute__((address_space(1))) void*)g,
      (__attribute__((address_space(3))) void*)l, 16, 0, 0);
}

__device__ __forceinline__ unsigned pk2(float a, float b) {
  union { bf16 h[2]; unsigned u; } t;
  t.h[0] = (bf16)a; t.h[1] = (bf16)b;
  return t.u;
}

// ---------------- elementwise prep ----------------

__global__ __launch_bounds__(256) void rope_cast(
    const float* __restrict__ x, bf16* __restrict__ xb, bf16* __restrict__ qr) {
  int idx = blockIdx.x * 256 + threadIdx.x;   // 0 .. NTOK*512
  int row = idx >> 9;
  int i = idx & 511;
  int h = i >> 5, d2 = i & 31;
  int pos = row & (SEQ - 1);
  int c0 = h * HD + d2;
  size_t base = (size_t)row * EMB;
  float x0 = x[base + c0], x1 = x[base + c0 + 32];
  float invf = exp2f(-(float)d2 * 0.4152410118609203f);
  float ang = (float)pos * invf;
  float sn, cs;
  sincosf(ang, &sn, &cs);
  qr[base + c0] = (bf16)(x0 * cs - x1 * sn);
  qr[base + c0 + 32] = (bf16)(x1 * cs + x0 * sn);
  xb[base + c0] = (bf16)x0;
  xb[base + c0 + 32] = (bf16)x1;
}

// all three weight casts in one launch
__global__ __launch_bounds__(256) void cast_all(
    const float* __restrict__ w0, const float* __restrict__ w1,
    const float* __restrict__ w2, bf16* __restrict__ o0,
    bf16* __restrict__ o1, bf16* __restrict__ o2) {
  int i = (blockIdx.x * 256 + threadIdx.x) * 4;
  const float* s; bf16* d; int off;
  if (i < 3 * 1024 * 1024) { s = w0; d = o0; off = i; }
  else if (i < 4 * 1024 * 1024) { s = w1; d = o1; off = i - 3 * 1024 * 1024; }
  else { s = w2; d = o2; off = i - 4 * 1024 * 1024; }
  float4 f = *(const float4*)(s + off);
  d[off] = (bf16)f.x; d[off + 1] = (bf16)f.y;
  d[off + 2] = (bf16)f.z; d[off + 3] = (bf16)f.w;
}

// ---------------- fused in-proj GEMM ----------------
// Outputs: qb[token][1024] pre-scaled by 0.125; kv images per (b,h): 32 tiles
// of 64 keys, each {K 4096 elem | V 4096 elem} in the exact attention LDS
// layout. K pre-scaled by log2(e).
__global__ __launch_bounds__(256) void gemm_in(
    const bf16* __restrict__ Aq, const bf16* __restrict__ Ax,
    const bf16* __restrict__ W, const float* __restrict__ bias,
    bf16* __restrict__ qb, bf16* __restrict__ kv) {
  __shared__ bf16 As[128 * 32];
  __shared__ bf16 Bs[128 * 32];
  const int tid = threadIdx.x, lane = tid & 63, wave = tid >> 6;
  const int quad = lane >> 4, l16 = lane & 15;
  const int m0 = blockIdx.y * 128, n0 = blockIdx.x * 128;
  const bf16* A = (n0 < 2048) ? Aq : Ax;
  const int K = 1024;
  const int wm = (wave >> 1) * 64, wn = (wave & 1) * 64;
  const int srow = wave * 32 + (lane >> 2);
  const int scol = (lane & 3) * 8;
  f32x4 acc[4][4] = {};
  for (int k0 = 0; k0 < K; k0 += 32) {
    __syncthreads();
    gll16(A + (size_t)(m0 + srow) * K + k0 + scol, As + wave * 1024);
    gll16(A + (size_t)(m0 + srow + 16) * K + k0 + scol, As + wave * 1024 + 512);
    gll16(W + (size_t)(n0 + srow) * K + k0 + scol, Bs + wave * 1024);
    gll16(W + (size_t)(n0 + srow + 16) * K + k0 + scol, Bs + wave * 1024 + 512);
    __syncthreads();
    bf16x8 af[4], bw[4];
#pragma unroll
    for (int t = 0; t < 4; ++t) {
      af[t] = *(const bf16x8*)(As + (wm + t * 16 + l16) * 32 + quad * 8);
      bw[t] = *(const bf16x8*)(Bs + (wn + t * 16 + l16) * 32 + quad * 8);
    }
#pragma unroll
    for (int mt = 0; mt < 4; ++mt)
#pragma unroll
      for (int nt = 0; nt < 4; ++nt)
        acc[mt][nt] = mfma16(af[mt], bw[nt], acc[mt][nt]);
  }
  if (n0 < 1024) {
    // Q: scale 1/8 (exact in bf16)
#pragma unroll
    for (int mt = 0; mt < 4; ++mt)
      for (int nt = 0; nt < 4; ++nt) {
        const int n = n0 + wn + nt * 16 + l16;
        const float bv = bias[n];
#pragma unroll
        for (int r = 0; r < 4; ++r) {
          const int m = m0 + wm + mt * 16 + quad * 4 + r;
          qb[(size_t)m * 1024 + n] = (bf16)((acc[mt][nt][r] + bv) * 0.125f);
        }
      }
  } else if (n0 < 2048) {
    // K: scale log2(e), write into swizzled 64-key tile image
#pragma unroll
    for (int mt = 0; mt < 4; ++mt)
      for (int nt = 0; nt < 4; ++nt) {
        const int n = n0 + wn + nt * 16 + l16;
        const float bv = bias[n];
        const int kd = n - 1024, hh = kd >> 6, d = kd & 63;
        const int dc = d >> 3, dl = d & 7;
#pragma unroll
        for (int r = 0; r < 4; ++r) {
          const int m = m0 + wm + mt * 16 + quad * 4 + r;
          const int bb = m >> 11, s = m & 2047;
          const int t = s >> 6, kr = s & 63;
          const size_t base = ((size_t)((bb * 16 + hh) * 32 + t)) * 8192;
          kv[base + kr * 64 + ((dc ^ (kr & 7)) << 3) + dl] =
              (bf16)((acc[mt][nt][r] + bv) * 1.4426950408889634f);
        }
      }
  } else {
    // V: permuted+swizzled 64-key tile image, 4 tokens per bf16x4
#pragma unroll
    for (int mt = 0; mt < 4; ++mt)
      for (int nt = 0; nt < 4; ++nt) {
        const int n = n0 + wn + nt * 16 + l16;
        const float bv = bias[n];
        const int vd = n - 2048, hh = vd >> 6, d = vd & 63;
        const int m = m0 + wm + mt * 16 + quad * 4;
        const int bb = m >> 11, s = m & 2047;
        const int t = s >> 6, kt = s & 63;
        const int g = kt >> 4, w = kt & 15;
        const int c = 2 * g + ((w >> 2) & 1);
        const int slot = (w & 8) ? 4 : 0;
        const size_t base = ((size_t)((bb * 16 + hh) * 32 + t)) * 8192 + 4096;
        bf16x4 pkv;
#pragma unroll
        for (int r = 0; r < 4; ++r) pkv[r] = (bf16)(acc[mt][nt][r] + bv);
        *(bf16x4*)(kv + base + d * 64 + ((c ^ (d & 7)) << 3) + slot) = pkv;
      }
  }
}

// ---------------- GEMM 128x128: C = A @ W^T + bias ----------------
__global__ __launch_bounds__(256) void gemm_bt(
    const bf16* __restrict__ A, const bf16* __restrict__ W,
    const float* __restrict__ bias,
    float* __restrict__ outF, bf16* __restrict__ outB,
    int M, int N, int K) {
  __shared__ bf16 As[128 * 32];
  __shared__ bf16 Bs[128 * 32];
  const int tid = threadIdx.x, lane = tid & 63, wave = tid >> 6;
  const int quad = lane >> 4, l16 = lane & 15;
  const int m0 = blockIdx.y * 128, n0 = blockIdx.x * 128;
  const int wm = (wave >> 1) * 64, wn = (wave & 1) * 64;
  const int srow = wave * 32 + (lane >> 2);
  const int scol = (lane & 3) * 8;
  f32x4 acc[4][4] = {};
  for (int k0 = 0; k0 < K; k0 += 32) {
    __syncthreads();
    gll16(A + (size_t)(m0 + srow) * K + k0 + scol, As + wave * 1024);
    gll16(A + (size_t)(m0 + srow + 16) * K + k0 + scol, As + wave * 1024 + 512);
    gll16(W + (size_t)(n0 + srow) * K + k0 + scol, Bs + wave * 1024);
    gll16(W + (size_t)(n0 + srow + 16) * K + k0 + scol, Bs + wave * 1024 + 512);
    __syncthreads();
    bf16x8 af[4], bw[4];
#pragma unroll
    for (int t = 0; t < 4; ++t) {
      af[t] = *(const bf16x8*)(As + (wm + t * 16 + l16) * 32 + quad * 8);
      bw[t] = *(const bf16x8*)(Bs + (wn + t * 16 + l16) * 32 + quad * 8);
    }
#pragma unroll
    for (int mt = 0; mt < 4; ++mt)
#pragma unroll
      for (int nt = 0; nt < 4; ++nt)
        acc[mt][nt] = mfma16(af[mt], bw[nt], acc[mt][nt]);
  }
#pragma unroll
  for (int mt = 0; mt < 4; ++mt)
    for (int nt = 0; nt < 4; ++nt) {
      const int n = n0 + wn + nt * 16 + l16;
      const float bv = bias ? bias[n] : 0.0f;
#pragma unroll
      for (int r = 0; r < 4; ++r) {
        const int m = m0 + wm + mt * 16 + quad * 4 + r;
        const float v = acc[mt][nt][r] + bv;
        if (outF) outF[(size_t)m * N + n] = v;
        if (outB) outB[(size_t)m * N + n] = (bf16)v;
      }
    }
}

// ---------------- GEMM 128x64 tiles ----------------
__global__ __launch_bounds__(256) void gemm_bt64(
    const bf16* __restrict__ A, const bf16* __restrict__ W,
    const float* __restrict__ bias, float* __restrict__ outF,
    int M, int N, int K) {
  __shared__ bf16 As[128 * 32];
  __shared__ bf16 Bs[64 * 32];
  const int tid = threadIdx.x, lane = tid & 63, wave = tid >> 6;
  const int quad = lane >> 4, l16 = lane & 15;
  const int m0 = blockIdx.y * 128, n0 = blockIdx.x * 64;
  const int wm = (wave >> 1) * 64, wn = (wave & 1) * 32;
  const int srow = wave * 32 + (lane >> 2);
  const int srowB = wave * 16 + (lane >> 2);
  const int scol = (lane & 3) * 8;
  f32x4 acc[4][2] = {};
  for (int k0 = 0; k0 < K; k0 += 32) {
    __syncthreads();
    gll16(A + (size_t)(m0 + srow) * K + k0 + scol, As + wave * 1024);
    gll16(A + (size_t)(m0 + srow + 16) * K + k0 + scol, As + wave * 1024 + 512);
    gll16(W + (size_t)(n0 + srowB) * K + k0 + scol, Bs + wave * 512);
    __syncthreads();
    bf16x8 af[4], bw[2];
#pragma unroll
    for (int t = 0; t < 4; ++t)
      af[t] = *(const bf16x8*)(As + (wm + t * 16 + l16) * 32 + quad * 8);
#pragma unroll
    for (int t = 0; t < 2; ++t)
      bw[t] = *(const bf16x8*)(Bs + (wn + t * 16 + l16) * 32 + quad * 8);
#pragma unroll
    for (int mt = 0; mt < 4; ++mt)
#pragma unroll
      for (int nt = 0; nt < 2; ++nt)
        acc[mt][nt] = mfma16(af[mt], bw[nt], acc[mt][nt]);
  }
#pragma unroll
  for (int mt = 0; mt < 4; ++mt)
    for (int nt = 0; nt < 2; ++nt) {
      const int n = n0 + wn + nt * 16 + l16;
      const float bv = bias[n];
#pragma unroll
      for (int r = 0; r < 4; ++r) {
        const int m = m0 + wm + mt * 16 + quad * 4 + r;
        outF[(size_t)m * N + n] = acc[mt][nt][r] + bv;
      }
    }
}

// ---------------- flash attention v12: split-K, register diet ----------------
// 512 blocks x 512 threads. Waves 0-3: keys 0-1023; waves 4-7: keys 1024-2047.
// 64-key tiles, per-group double buffer (LDS 64KB total), partial O/L combined
// in-block via LDS at the end. Denominator: VALU lpart (no lacc accumulator).
__global__ __launch_bounds__(512, 4) void attn12(
    const bf16* __restrict__ Q, const bf16* __restrict__ KV,
    bf16* __restrict__ ctx) {
  __shared__ __align__(16) bf16 kvb[2][2][8192];  // [group][buf][K 4096|V 4096]
  const int tid = threadIdx.x, lane = tid & 63, wave = tid >> 6;
  const int grp = wave >> 2, lw = wave & 3;
  const int hi = lane >> 5, l31 = lane & 31, l7 = lane & 7;
  const int bid = blockIdx.x;
  const int hb = (bid & 7) * 4 + ((bid >> 3) & 3);
  const int qt = bid >> 5;              // 0..15
  const int h = hb & 15, b = hb >> 4;

  // Q B-frags (lane owns col q = l31; k=d=tt*16+hi*8+j), producer-scaled 1/8
  bf16x8 qf[4];
  {
    const int qrow = qt * 128 + lw * 32 + l31;
    const bf16* qp = Q + (size_t)(b * SEQ + qrow) * 1024 + h * HD + hi * 8;
#pragma unroll
    for (int t = 0; t < 4; ++t) qf[t] = *(const bf16x8*)(qp + t * 16);
  }
  // staging: group's tile stream (16 tiles of 8192 elems), 4 x gll16/thread
  const int soff = lw * 2048 + lane * 8;
  const bf16* kvg = KV + ((size_t)((b * NH + h) * 32 + grp * 16)) * 8192 + soff;
  bf16* myb[2] = {&kvb[grp][0][0], &kvb[grp][1][0]};
#pragma unroll
  for (int i = 0; i < 4; ++i)           // stage tile 0 into buf 0
    gll16(kvg + i * 512, myb[0] + soff + i * 512);

  f32x16 o0 = {}, o1 = {};
  float lpart = 0.0f;
  const f32x16 zf = {};

  for (int t = 0; t < 16; ++t) {
    __syncthreads();                    // buf[t&1] ready for all waves
    if (t + 1 < 16) {                   // prefetch next tile into other buffer
      const bf16* src = kvg + (size_t)(t + 1) * 8192;
      bf16* dst = myb[(t + 1) & 1] + soff;
#pragma unroll
      for (int i = 0; i < 4; ++i) gll16(src + i * 512, dst + i * 512);
    }
    const bf16* ks = myb[t & 1];
    const bf16* vs = ks + 4096;
    f32x16 s0, s1;
    __builtin_amdgcn_s_setprio(1);
    {
      const int swc = (hi ^ l7) * 8;
      bf16x8 k0 = *(const bf16x8*)(ks + l31 * 64 + swc);
      bf16x8 k1 = *(const bf16x8*)(ks + (32 + l31) * 64 + swc);
      s0 = mfma32(k0, qf[0], zf);       // zero-C: no per-tile re-zero movs
      s1 = mfma32(k1, qf[0], zf);
    }
#pragma unroll
    for (int tt = 1; tt < 4; ++tt) {
      const int swc = ((tt * 2 + hi) ^ l7) * 8;
      bf16x8 k0 = *(const bf16x8*)(ks + l31 * 64 + swc);
      bf16x8 k1 = *(const bf16x8*)(ks + (32 + l31) * 64 + swc);
      s0 = mfma32(k0, qf[tt], s0);
      s1 = mfma32(k1, qf[tt], s1);
    }
    __builtin_amdgcn_s_setprio(0);
    unsigned u[16];
#pragma unroll
    for (int g = 0; g < 8; ++g) {
      const int base = (g & 3) * 4;
      float e0, e1, e2, e3;
      if (g < 4) {
        e0 = __builtin_amdgcn_exp2f(s0[base]);
        e1 = __builtin_amdgcn_exp2f(s0[base + 1]);
        e2 = __builtin_amdgcn_exp2f(s0[base + 2]);
        e3 = __builtin_amdgcn_exp2f(s0[base + 3]);
      } else {
        e0 = __builtin_amdgcn_exp2f(s1[base]);
        e1 = __builtin_amdgcn_exp2f(s1[base + 1]);
        e2 = __builtin_amdgcn_exp2f(s1[base + 2]);
        e3 = __builtin_amdgcn_exp2f(s1[base + 3]);
      }
      lpart += (e0 + e1) + (e2 + e3);
      u[g * 2] = pk2(e0, e1);
      u[g * 2 + 1] = pk2(e2, e3);
    }
    // PV: chunk = (2kk + hi) ^ l7
    __builtin_amdgcn_s_setprio(1);
#pragma unroll
    for (int kk = 0; kk < 4; ++kk) {
      union { unsigned w[4]; bf16x8 v; } fw;
      fw.w[0] = u[4 * kk]; fw.w[1] = u[4 * kk + 1];
      fw.w[2] = u[4 * kk + 2]; fw.w[3] = u[4 * kk + 3];
      const int c16 = (2 * kk + hi) ^ l7;
      bf16x8 v0 = *(const bf16x8*)(vs + l31 * 64 + c16 * 8);
      bf16x8 v1 = *(const bf16x8*)(vs + (32 + l31) * 64 + c16 * 8);
      o0 = mfma32(fw.v, v0, o0);
      o1 = mfma32(fw.v, v1, o1);
    }
    __builtin_amdgcn_s_setprio(0);
  }
  // in-block split-K combine: group 1 parks partials in LDS (reuses kvb).
  // Park stride 33 floats -> lane*33 mod 32 = lane mod 32: conflict-free.
  __syncthreads();
  float* fred = (float*)&kvb[0][0][0];  // 16384 floats total
  if (grp == 1) {
    float* p = fred + (size_t)(lw * 64 + lane) * 33;
#pragma unroll
    for (int r = 0; r < 16; ++r) { p[r] = o0[r]; p[16 + r] = o1[r]; }
    p[32] = lpart;
  }
  __syncthreads();
  if (grp == 0) {
    const float* p = fred + (size_t)(lw * 64 + lane) * 33;
    float lt = lpart + p[32];           // own + group1, same (hi, q=l31)
    lt += __shfl_xor(lt, 32, 64);       // + other hi half -> total over 2048 keys
    float* Lv = fred + 8448 + lw * 32;  // past the park region
    if (lane < 32) Lv[l31] = 1.0f / lt;
    // same-wave LDS write->read (v9-proven, no barrier needed)
#pragma unroll
    for (int r = 0; r < 16; ++r) {
      const int qloc = (r & 3) + 8 * (r >> 2) + 4 * hi;
      const float inv = Lv[qloc];
      const int qrow = qt * 128 + lw * 32 + qloc;
      bf16* cp = ctx + (size_t)(b * SEQ + qrow) * EMB + h * HD;
      cp[l31] = (bf16)((o0[r] + p[r]) * inv);
      cp[32 + l31] = (bf16)((o1[r] + p[16 + r]) * inv);
    }
  }
}

// ---------------- residual + LayerNorm ----------------
__global__ __launch_bounds__(256) void ln1_k(
    const float* __restrict__ x, const float* __restrict__ ao,
    const float* __restrict__ g, const float* __restrict__ bta,
    float* __restrict__ hF, bf16* __restrict__ hB) {
  int row = blockIdx.x, tid = threadIdx.x;
  const float* xr = x + (size_t)row * EMB;
  const float* ar = ao + (size_t)row * EMB;
  float v[4], s = 0.0f, s2 = 0.0f;
#pragma unroll
  for (int i = 0; i < 4; ++i) {
    float t = xr[tid + i * 256] + ar[tid + i * 256];
    v[i] = t; s += t; s2 += t * t;
  }
#pragma unroll
  for (int off = 1; off < 64; off <<= 1) {
    s += __shfl_xor(s, off, 64);
    s2 += __shfl_xor(s2, off, 64);
  }
  __shared__ float red[8];
  int wave = tid >> 6, lane = tid & 63;
  if (lane == 0) { red[wave] = s; red[4 + wave] = s2; }
  __syncthreads();
  s = red[0] + red[1] + red[2] + red[3];
  s2 = red[4] + red[5] + red[6] + red[7];
  float mean = s * (1.0f / EMB);
  float var = s2 * (1.0f / EMB) - mean * mean;
  float inv = rsqrtf(var + 1e-5f);
#pragma unroll
  for (int i = 0; i < 4; ++i) {
    int c = tid + i * 256;
    float t = (v[i] - mean) * inv * g[c] + bta[c];
    hF[(size_t)row * EMB + c] = t;
    hB[(size_t)row * EMB + c] = (bf16)t;
  }
}

__global__ __launch_bounds__(256) void geglu_ln2(
    const float* __restrict__ h, const bf16* __restrict__ proj,
    const float* __restrict__ g, const float* __restrict__ bta,
    float* __restrict__ out) {
  int row = blockIdx.x, tid = threadIdx.x;
  const float* hr = h + (size_t)row * EMB;
  const bf16* pr = proj + (size_t)row * 2048;
  float v[4], s = 0.0f, s2 = 0.0f;
#pragma unroll
  for (int i = 0; i < 4; ++i) {
    int c = tid + i * 256;
    float val = (float)pr[c];
    float gate = (float)pr[1024 + c];
    float ge = 0.5f * gate * (1.0f + erff(gate * 0.70710678f));
    float t = hr[c] + val * ge;
    v[i] = t; s += t; s2 += t * t;
  }
#pragma unroll
  for (int off = 1; off < 64; off <<= 1) {
    s += __shfl_xor(s, off, 64);
    s2 += __shfl_xor(s2, off, 64);
  }
  __shared__ float red[8];
  int wave = tid >> 6, lane = tid & 63;
  if (lane == 0) { red[wave] = s; red[4 + wave] = s2; }
  __syncthreads();
  s = red[0] + red[1] + red[2] + red[3];
  s2 = red[4] + red[5] + red[6] + red[7];
  float mean = s * (1.0f / EMB);
  float var = s2 * (1.0f / EMB) - mean * mean;
  float inv = rsqrtf(var + 1e-5f);
#pragma unroll
  for (int i = 0; i < 4; ++i) {
    int c = tid + i * 256;
    out[(size_t)row * EMB + c] = (v[i] - mean) * inv * g[c] + bta[c];
  }
}

extern "C" void kernel_launch(void* const* d_in, const int* in_sizes, int n_in,
                              void* d_out, int out_size, void* d_ws, size_t ws_size,
                              hipStream_t stream) {
  const float* x = (const float*)d_in[0];
  const float* inW = (const float*)d_in[1];
  const float* inB = (const float*)d_in[2];
  const float* outW = (const float*)d_in[3];
  const float* opB = (const float*)d_in[4];
  const float* ggW = (const float*)d_in[5];
  const float* ggB = (const float*)d_in[6];
  const float* g1 = (const float*)d_in[7];
  const float* b1 = (const float*)d_in[8];
  const float* g2 = (const float*)d_in[9];
  const float* b2 = (const float*)d_in[10];
  float* out = (float*)d_out;
  char* ws = (char*)d_ws;
  const size_t MB = 1ull << 20;
  bf16* xb = (bf16*)(ws);              // 8 MB, dead after gemm_in
  bf16* hB = (bf16*)(ws);              // overlays xb (ln1 out)
  bf16* qr = (bf16*)(ws + 8 * MB);     // 8 MB, dead after gemm_in
  bf16* ctx = (bf16*)(ws + 8 * MB);    // overlays qr (attn output)
  bf16* wI = (bf16*)(ws + 16 * MB);    // 6 MB
  bf16* wO = (bf16*)(ws + 22 * MB);    // 2 MB
  bf16* wG = (bf16*)(ws + 24 * MB);    // 4 MB
  bf16* qb = (bf16*)(ws + 28 * MB);    // 8 MB, dead after attn
  bf16* kv = (bf16*)(ws + 36 * MB);    // 16 MB tile images, dead after attn
  bf16* projB = (bf16*)(ws + 28 * MB); // overlays qb+kv (GeGLU proj)
  float* ao = (float*)(ws + 52 * MB);  // 16 MB f32

  rope_cast<<<NTOK * 512 / 256, 256, 0, stream>>>(x, xb, qr);
  cast_all<<<6144, 256, 0, stream>>>(inW, outW, ggW, wI, wO, wG);
  gemm_in<<<dim3(24, 32), 256, 0, stream>>>(qr, xb, wI, inB, qb, kv);
  attn12<<<512, 512, 0, stream>>>(qb, kv, ctx);
  gemm_bt64<<<dim3(16, 32), 256, 0, stream>>>(ctx, wO, opB, ao,
                                              NTOK, 1024, 1024);
  ln1_k<<<NTOK, 256, 0, stream>>>(x, ao, g1, b1, ao, hB);
  gemm_bt<<<dim3(16, 32), 256, 0, stream>>>(hB, wG, ggB, nullptr, projB,
                                            NTOK, 2048, 1024);
  geglu_ln2<<<NTOK, 256, 0, stream>>>(ao, projB, g2, b2, out);
}

// Round 4
// 276.277 us; speedup vs baseline: 1.0936x; 1.0071x over previous
//
#include <hip/hip_runtime.h>

// TransformerBlock on MI355X (gfx950).
// v13: attention de-lockstep. 256-thread blocks (4 waves x 32 q = 128 q), each
// block scans ALL 2048 keys (32 x 64-key pre-swizzled tile images). LDS is
// TRIPLE-buffered (3 x 16KB) with prefetch depth 2; barriers are raw s_barrier
// with counted s_waitcnt vmcnt(4) (never 0 in-loop) so staging loads stay in
// flight across barriers (T3/T4). launch_bounds(256,3) -> 170-reg budget (no
// AGPR thrash), 3 independent blocks/CU that phase-shift against each other.
// Producer-side K/V images, exp2, producer-folded scales as in v12.

typedef __bf16 bf16;
typedef bf16 bf16x8 __attribute__((ext_vector_type(8)));
typedef bf16 bf16x4 __attribute__((ext_vector_type(4)));
typedef float f32x4 __attribute__((ext_vector_type(4)));
typedef float f32x16 __attribute__((ext_vector_type(16)));

#define EMB 1024
#define SEQ 2048
#define NTOK 4096
#define NH 16
#define HD 64

__device__ __forceinline__ f32x4 mfma16(bf16x8 a, bf16x8 b, f32x4 c) {
  return __builtin_amdgcn_mfma_f32_16x16x32_bf16(a, b, c, 0, 0, 0);
}
__device__ __forceinline__ f32x16 mfma32(bf16x8 a, bf16x8 b, f32x16 c) {
  return __builtin_amdgcn_mfma_f32_32x32x16_bf16(a, b, c, 0, 0, 0);
}

__device__ __forceinline__ void gll16(const void* g, void* l) {
  __builtin_amdgcn_global_load_lds(
      (const __attribute__((address_space(1))) void*)g,
      (__attribute__((address_space(3))) void*)l, 16, 0, 0);
}

__device__ __forceinline__ unsigned pk2(float a, float b) {
  union { bf16 h[2]; unsigned u; } t;
  t.h[0] = (bf16)a; t.h[1] = (bf16)b;
  return t.u;
}

// ---------------- elementwise prep ----------------

__global__ __launch_bounds__(256) void rope_cast(
    const float* __restrict__ x, bf16* __restrict__ xb, bf16* __restrict__ qr) {
  int idx = blockIdx.x * 256 + threadIdx.x;   // 0 .. NTOK*512
  int row = idx >> 9;
  int i = idx & 511;
  int h = i >> 5, d2 = i & 31;
  int pos = row & (SEQ - 1);
  int c0 = h * HD + d2;
  size_t base = (size_t)row * EMB;
  float x0 = x[base + c0], x1 = x[base + c0 + 32];
  float invf = exp2f(-(float)d2 * 0.4152410118609203f);
  float ang = (float)pos * invf;
  float sn, cs;
  sincosf(ang, &sn, &cs);
  qr[base + c0] = (bf16)(x0 * cs - x1 * sn);
  qr[base + c0 + 32] = (bf16)(x1 * cs + x0 * sn);
  xb[base + c0] = (bf16)x0;
  xb[base + c0 + 32] = (bf16)x1;
}

// all three weight casts in one launch
__global__ __launch_bounds__(256) void cast_all(
    const float* __restrict__ w0, const float* __restrict__ w1,
    const float* __restrict__ w2, bf16* __restrict__ o0,
    bf16* __restrict__ o1, bf16* __restrict__ o2) {
  int i = (blockIdx.x * 256 + threadIdx.x) * 4;
  const float* s; bf16* d; int off;
  if (i < 3 * 1024 * 1024) { s = w0; d = o0; off = i; }
  else if (i < 4 * 1024 * 1024) { s = w1; d = o1; off = i - 3 * 1024 * 1024; }
  else { s = w2; d = o2; off = i - 4 * 1024 * 1024; }
  float4 f = *(const float4*)(s + off);
  d[off] = (bf16)f.x; d[off + 1] = (bf16)f.y;
  d[off + 2] = (bf16)f.z; d[off + 3] = (bf16)f.w;
}

// ---------------- fused in-proj GEMM ----------------
// Outputs: qb[token][1024] pre-scaled by 0.125; kv images per (b,h): 32 tiles
// of 64 keys, each {K 4096 elem | V 4096 elem} in the exact attention LDS
// layout. K pre-scaled by log2(e).
__global__ __launch_bounds__(256) void gemm_in(
    const bf16* __restrict__ Aq, const bf16* __restrict__ Ax,
    const bf16* __restrict__ W, const float* __restrict__ bias,
    bf16* __restrict__ qb, bf16* __restrict__ kv) {
  __shared__ bf16 As[128 * 32];
  __shared__ bf16 Bs[128 * 32];
  const int tid = threadIdx.x, lane = tid & 63, wave = tid >> 6;
  const int quad = lane >> 4, l16 = lane & 15;
  const int m0 = blockIdx.y * 128, n0 = blockIdx.x * 128;
  const bf16* A = (n0 < 2048) ? Aq : Ax;
  const int K = 1024;
  const int wm = (wave >> 1) * 64, wn = (wave & 1) * 64;
  const int srow = wave * 32 + (lane >> 2);
  const int scol = (lane & 3) * 8;
  f32x4 acc[4][4] = {};
  for (int k0 = 0; k0 < K; k0 += 32) {
    __syncthreads();
    gll16(A + (size_t)(m0 + srow) * K + k0 + scol, As + wave * 1024);
    gll16(A + (size_t)(m0 + srow + 16) * K + k0 + scol, As + wave * 1024 + 512);
    gll16(W + (size_t)(n0 + srow) * K + k0 + scol, Bs + wave * 1024);
    gll16(W + (size_t)(n0 + srow + 16) * K + k0 + scol, Bs + wave * 1024 + 512);
    __syncthreads();
    bf16x8 af[4], bw[4];
#pragma unroll
    for (int t = 0; t < 4; ++t) {
      af[t] = *(const bf16x8*)(As + (wm + t * 16 + l16) * 32 + quad * 8);
      bw[t] = *(const bf16x8*)(Bs + (wn + t * 16 + l16) * 32 + quad * 8);
    }
#pragma unroll
    for (int mt = 0; mt < 4; ++mt)
#pragma unroll
      for (int nt = 0; nt < 4; ++nt)
        acc[mt][nt] = mfma16(af[mt], bw[nt], acc[mt][nt]);
  }
  if (n0 < 1024) {
    // Q: scale 1/8 (exact in bf16)
#pragma unroll
    for (int mt = 0; mt < 4; ++mt)
      for (int nt = 0; nt < 4; ++nt) {
        const int n = n0 + wn + nt * 16 + l16;
        const float bv = bias[n];
#pragma unroll
        for (int r = 0; r < 4; ++r) {
          const int m = m0 + wm + mt * 16 + quad * 4 + r;
          qb[(size_t)m * 1024 + n] = (bf16)((acc[mt][nt][r] + bv) * 0.125f);
        }
      }
  } else if (n0 < 2048) {
    // K: scale log2(e), write into swizzled 64-key tile image
#pragma unroll
    for (int mt = 0; mt < 4; ++mt)
      for (int nt = 0; nt < 4; ++nt) {
        const int n = n0 + wn + nt * 16 + l16;
        const float bv = bias[n];
        const int kd = n - 1024, hh = kd >> 6, d = kd & 63;
        const int dc = d >> 3, dl = d & 7;
#pragma unroll
        for (int r = 0; r < 4; ++r) {
          const int m = m0 + wm + mt * 16 + quad * 4 + r;
          const int bb = m >> 11, s = m & 2047;
          const int t = s >> 6, kr = s & 63;
          const size_t base = ((size_t)((bb * 16 + hh) * 32 + t)) * 8192;
          kv[base + kr * 64 + ((dc ^ (kr & 7)) << 3) + dl] =
              (bf16)((acc[mt][nt][r] + bv) * 1.4426950408889634f);
        }
      }
  } else {
    // V: permuted+swizzled 64-key tile image, 4 tokens per bf16x4
#pragma unroll
    for (int mt = 0; mt < 4; ++mt)
      for (int nt = 0; nt < 4; ++nt) {
        const int n = n0 + wn + nt * 16 + l16;
        const float bv = bias[n];
        const int vd = n - 2048, hh = vd >> 6, d = vd & 63;
        const int m = m0 + wm + mt * 16 + quad * 4;
        const int bb = m >> 11, s = m & 2047;
        const int t = s >> 6, kt = s & 63;
        const int g = kt >> 4, w = kt & 15;
        const int c = 2 * g + ((w >> 2) & 1);
        const int slot = (w & 8) ? 4 : 0;
        const size_t base = ((size_t)((bb * 16 + hh) * 32 + t)) * 8192 + 4096;
        bf16x4 pkv;
#pragma unroll
        for (int r = 0; r < 4; ++r) pkv[r] = (bf16)(acc[mt][nt][r] + bv);
        *(bf16x4*)(kv + base + d * 64 + ((c ^ (d & 7)) << 3) + slot) = pkv;
      }
  }
}

// ---------------- GEMM 128x128: C = A @ W^T + bias ----------------
__global__ __launch_bounds__(256) void gemm_bt(
    const bf16* __restrict__ A, const bf16* __restrict__ W,
    const float* __restrict__ bias,
    float* __restrict__ outF, bf16* __restrict__ outB,
    int M, int N, int K) {
  __shared__ bf16 As[128 * 32];
  __shared__ bf16 Bs[128 * 32];
  const int tid = threadIdx.x, lane = tid & 63, wave = tid >> 6;
  const int quad = lane >> 4, l16 = lane & 15;
  const int m0 = blockIdx.y * 128, n0 = blockIdx.x * 128;
  const int wm = (wave >> 1) * 64, wn = (wave & 1) * 64;
  const int srow = wave * 32 + (lane >> 2);
  const int scol = (lane & 3) * 8;
  f32x4 acc[4][4] = {};
  for (int k0 = 0; k0 < K; k0 += 32) {
    __syncthreads();
    gll16(A + (size_t)(m0 + srow) * K + k0 + scol, As + wave * 1024);
    gll16(A + (size_t)(m0 + srow + 16) * K + k0 + scol, As + wave * 1024 + 512);
    gll16(W + (size_t)(n0 + srow) * K + k0 + scol, Bs + wave * 1024);
    gll16(W + (size_t)(n0 + srow + 16) * K + k0 + scol, Bs + wave * 1024 + 512);
    __syncthreads();
    bf16x8 af[4], bw[4];
#pragma unroll
    for (int t = 0; t < 4; ++t) {
      af[t] = *(const bf16x8*)(As + (wm + t * 16 + l16) * 32 + quad * 8);
      bw[t] = *(const bf16x8*)(Bs + (wn + t * 16 + l16) * 32 + quad * 8);
    }
#pragma unroll
    for (int mt = 0; mt < 4; ++mt)
#pragma unroll
      for (int nt = 0; nt < 4; ++nt)
        acc[mt][nt] = mfma16(af[mt], bw[nt], acc[mt][nt]);
  }
#pragma unroll
  for (int mt = 0; mt < 4; ++mt)
    for (int nt = 0; nt < 4; ++nt) {
      const int n = n0 + wn + nt * 16 + l16;
      const float bv = bias ? bias[n] : 0.0f;
#pragma unroll
      for (int r = 0; r < 4; ++r) {
        const int m = m0 + wm + mt * 16 + quad * 4 + r;
        const float v = acc[mt][nt][r] + bv;
        if (outF) outF[(size_t)m * N + n] = v;
        if (outB) outB[(size_t)m * N + n] = (bf16)v;
      }
    }
}

// ---------------- GEMM 128x64 tiles ----------------
__global__ __launch_bounds__(256) void gemm_bt64(
    const bf16* __restrict__ A, const bf16* __restrict__ W,
    const float* __restrict__ bias, float* __restrict__ outF,
    int M, int N, int K) {
  __shared__ bf16 As[128 * 32];
  __shared__ bf16 Bs[64 * 32];
  const int tid = threadIdx.x, lane = tid & 63, wave = tid >> 6;
  const int quad = lane >> 4, l16 = lane & 15;
  const int m0 = blockIdx.y * 128, n0 = blockIdx.x * 64;
  const int wm = (wave >> 1) * 64, wn = (wave & 1) * 32;
  const int srow = wave * 32 + (lane >> 2);
  const int srowB = wave * 16 + (lane >> 2);
  const int scol = (lane & 3) * 8;
  f32x4 acc[4][2] = {};
  for (int k0 = 0; k0 < K; k0 += 32) {
    __syncthreads();
    gll16(A + (size_t)(m0 + srow) * K + k0 + scol, As + wave * 1024);
    gll16(A + (size_t)(m0 + srow + 16) * K + k0 + scol, As + wave * 1024 + 512);
    gll16(W + (size_t)(n0 + srowB) * K + k0 + scol, Bs + wave * 512);
    __syncthreads();
    bf16x8 af[4], bw[2];
#pragma unroll
    for (int t = 0; t < 4; ++t)
      af[t] = *(const bf16x8*)(As + (wm + t * 16 + l16) * 32 + quad * 8);
#pragma unroll
    for (int t = 0; t < 2; ++t)
      bw[t] = *(const bf16x8*)(Bs + (wn + t * 16 + l16) * 32 + quad * 8);
#pragma unroll
    for (int mt = 0; mt < 4; ++mt)
#pragma unroll
      for (int nt = 0; nt < 2; ++nt)
        acc[mt][nt] = mfma16(af[mt], bw[nt], acc[mt][nt]);
  }
#pragma unroll
  for (int mt = 0; mt < 4; ++mt)
    for (int nt = 0; nt < 2; ++nt) {
      const int n = n0 + wn + nt * 16 + l16;
      const float bv = bias[n];
#pragma unroll
      for (int r = 0; r < 4; ++r) {
        const int m = m0 + wm + mt * 16 + quad * 4 + r;
        outF[(size_t)m * N + n] = acc[mt][nt][r] + bv;
      }
    }
}

// ---------------- flash attention v13 ----------------
// 512 blocks x 256 threads (4 waves x 32 q). Each block: all 2048 keys as
// 32 x 64-key tiles. Triple-buffered LDS, prefetch depth 2, counted vmcnt(4)
// + raw s_barrier (loads in flight across barriers). 3 blocks/CU.
__global__ __launch_bounds__(256, 3) void attn13(
    const bf16* __restrict__ Q, const bf16* __restrict__ KV,
    bf16* __restrict__ ctx) {
  __shared__ __align__(16) bf16 kvb[3][8192];   // [buf][K 4096 | V 4096]
  __shared__ float Linv[4][32];
  const int tid = threadIdx.x, lane = tid & 63, wave = tid >> 6;
  const int hi = lane >> 5, l31 = lane & 31, l7 = lane & 7;
  const int bid = blockIdx.x;
  const int hb = (bid & 7) * 4 + ((bid >> 3) & 3);
  const int qt = bid >> 5;              // 0..15
  const int h = hb & 15, b = hb >> 4;

  // Q B-frags (lane owns col q = l31; k=d=tt*16+hi*8+j), producer-scaled 1/8
  bf16x8 qf[4];
  {
    const int qrow = qt * 128 + wave * 32 + l31;
    const bf16* qp = Q + (size_t)(b * SEQ + qrow) * 1024 + h * HD + hi * 8;
#pragma unroll
    for (int t = 0; t < 4; ++t) qf[t] = *(const bf16x8*)(qp + t * 16);
  }
  // Drain Q loads now so the in-loop vmcnt counts track ONLY gll16 staging.
  asm volatile("s_waitcnt vmcnt(0)" ::: "memory");

  // staging: full 32-tile stream for (b,h); 256 threads x 16B x 4 = 16KB/tile
  const int soff = tid * 8;             // elements; = tid*16 bytes
  const bf16* kvg = KV + ((size_t)(b * NH + h) * 32) * 8192 + soff;
#pragma unroll
  for (int i = 0; i < 4; ++i)           // tile 0 -> buf 0
    gll16(kvg + i * 2048, kvb[0] + soff + i * 2048);
#pragma unroll
  for (int i = 0; i < 4; ++i)           // tile 1 -> buf 1
    gll16(kvg + 8192 + i * 2048, kvb[1] + soff + i * 2048);

  f32x16 o0 = {}, o1 = {};
  float lpart = 0.0f;
  const f32x16 zf = {};
  int rd = 0, wr = 2;                   // read buf for tile t; prefetch dest

  for (int t = 0; t < 32; ++t) {
    // wait own tile-t loads (4 newest = tile t+1 stay in flight), then sync
    if (t < 31) asm volatile("s_waitcnt vmcnt(4)" ::: "memory");
    else        asm volatile("s_waitcnt vmcnt(0)" ::: "memory");
    __builtin_amdgcn_s_barrier();
    __builtin_amdgcn_sched_barrier(0);
    if (t + 2 < 32) {                   // prefetch tile t+2 (depth 2)
      const bf16* src = kvg + (size_t)(t + 2) * 8192;
      bf16* dst = kvb[wr] + soff;
#pragma unroll
      for (int i = 0; i < 4; ++i) gll16(src + i * 2048, dst + i * 2048);
    }
    const bf16* ks = kvb[rd];
    const bf16* vs = ks + 4096;
    f32x16 s0, s1;
    __builtin_amdgcn_s_setprio(1);
    {
      const int swc = (hi ^ l7) * 8;
      bf16x8 k0 = *(const bf16x8*)(ks + l31 * 64 + swc);
      bf16x8 k1 = *(const bf16x8*)(ks + (32 + l31) * 64 + swc);
      s0 = mfma32(k0, qf[0], zf);       // zero-C: no per-tile re-zero movs
      s1 = mfma32(k1, qf[0], zf);
    }
#pragma unroll
    for (int tt = 1; tt < 4; ++tt) {
      const int swc = ((tt * 2 + hi) ^ l7) * 8;
      bf16x8 k0 = *(const bf16x8*)(ks + l31 * 64 + swc);
      bf16x8 k1 = *(const bf16x8*)(ks + (32 + l31) * 64 + swc);
      s0 = mfma32(k0, qf[tt], s0);
      s1 = mfma32(k1, qf[tt], s1);
    }
    __builtin_amdgcn_s_setprio(0);
    unsigned u[16];
#pragma unroll
    for (int g = 0; g < 8; ++g) {
      const int base = (g & 3) * 4;
      float e0, e1, e2, e3;
      if (g < 4) {
        e0 = __builtin_amdgcn_exp2f(s0[base]);
        e1 = __builtin_amdgcn_exp2f(s0[base + 1]);
        e2 = __builtin_amdgcn_exp2f(s0[base + 2]);
        e3 = __builtin_amdgcn_exp2f(s0[base + 3]);
      } else {
        e0 = __builtin_amdgcn_exp2f(s1[base]);
        e1 = __builtin_amdgcn_exp2f(s1[base + 1]);
        e2 = __builtin_amdgcn_exp2f(s1[base + 2]);
        e3 = __builtin_amdgcn_exp2f(s1[base + 3]);
      }
      lpart += (e0 + e1) + (e2 + e3);
      u[g * 2] = pk2(e0, e1);
      u[g * 2 + 1] = pk2(e2, e3);
    }
    // PV: chunk = (2kk + hi) ^ l7
    __builtin_amdgcn_s_setprio(1);
#pragma unroll
    for (int kk = 0; kk < 4; ++kk) {
      union { unsigned w[4]; bf16x8 v; } fw;
      fw.w[0] = u[4 * kk]; fw.w[1] = u[4 * kk + 1];
      fw.w[2] = u[4 * kk + 2]; fw.w[3] = u[4 * kk + 3];
      const int c16 = (2 * kk + hi) ^ l7;
      bf16x8 v0 = *(const bf16x8*)(vs + l31 * 64 + c16 * 8);
      bf16x8 v1 = *(const bf16x8*)(vs + (32 + l31) * 64 + c16 * 8);
      o0 = mfma32(fw.v, v0, o0);
      o1 = mfma32(fw.v, v1, o1);
    }
    __builtin_amdgcn_s_setprio(0);
    rd = (rd + 1 == 3) ? 0 : rd + 1;
    wr = (wr + 1 == 3) ? 0 : wr + 1;
  }
  // epilogue: lane (l31,hi) holds half the keys for q=l31; combine across hi
  float ltot = lpart + __shfl_xor(lpart, 32, 64);
  if (lane < 32) Linv[wave][lane] = 1.0f / ltot;
#pragma unroll
  for (int r = 0; r < 16; ++r) {
    const int qloc = (r & 3) + 8 * (r >> 2) + 4 * hi;
    const float inv = Linv[wave][qloc];
    const int qrow = qt * 128 + wave * 32 + qloc;
    bf16* cp = ctx + (size_t)(b * SEQ + qrow) * EMB + h * HD;
    cp[l31] = (bf16)(o0[r] * inv);
    cp[32 + l31] = (bf16)(o1[r] * inv);
  }
}

// ---------------- residual + LayerNorm ----------------
__global__ __launch_bounds__(256) void ln1_k(
    const float* __restrict__ x, const float* __restrict__ ao,
    const float* __restrict__ g, const float* __restrict__ bta,
    float* __restrict__ hF, bf16* __restrict__ hB) {
  int row = blockIdx.x, tid = threadIdx.x;
  const float* xr = x + (size_t)row * EMB;
  const float* ar = ao + (size_t)row * EMB;
  float v[4], s = 0.0f, s2 = 0.0f;
#pragma unroll
  for (int i = 0; i < 4; ++i) {
    float t = xr[tid + i * 256] + ar[tid + i * 256];
    v[i] = t; s += t; s2 += t * t;
  }
#pragma unroll
  for (int off = 1; off < 64; off <<= 1) {
    s += __shfl_xor(s, off, 64);
    s2 += __shfl_xor(s2, off, 64);
  }
  __shared__ float red[8];
  int wave = tid >> 6, lane = tid & 63;
  if (lane == 0) { red[wave] = s; red[4 + wave] = s2; }
  __syncthreads();
  s = red[0] + red[1] + red[2] + red[3];
  s2 = red[4] + red[5] + red[6] + red[7];
  float mean = s * (1.0f / EMB);
  float var = s2 * (1.0f / EMB) - mean * mean;
  float inv = rsqrtf(var + 1e-5f);
#pragma unroll
  for (int i = 0; i < 4; ++i) {
    int c = tid + i * 256;
    float t = (v[i] - mean) * inv * g[c] + bta[c];
    hF[(size_t)row * EMB + c] = t;
    hB[(size_t)row * EMB + c] = (bf16)t;
  }
}

__global__ __launch_bounds__(256) void geglu_ln2(
    const float* __restrict__ h, const bf16* __restrict__ proj,
    const float* __restrict__ g, const float* __restrict__ bta,
    float* __restrict__ out) {
  int row = blockIdx.x, tid = threadIdx.x;
  const float* hr = h + (size_t)row * EMB;
  const bf16* pr = proj + (size_t)row * 2048;
  float v[4], s = 0.0f, s2 = 0.0f;
#pragma unroll
  for (int i = 0; i < 4; ++i) {
    int c = tid + i * 256;
    float val = (float)pr[c];
    float gate = (float)pr[1024 + c];
    float ge = 0.5f * gate * (1.0f + erff(gate * 0.70710678f));
    float t = hr[c] + val * ge;
    v[i] = t; s += t; s2 += t * t;
  }
#pragma unroll
  for (int off = 1; off < 64; off <<= 1) {
    s += __shfl_xor(s, off, 64);
    s2 += __shfl_xor(s2, off, 64);
  }
  __shared__ float red[8];
  int wave = tid >> 6, lane = tid & 63;
  if (lane == 0) { red[wave] = s; red[4 + wave] = s2; }
  __syncthreads();
  s = red[0] + red[1] + red[2] + red[3];
  s2 = red[4] + red[5] + red[6] + red[7];
  float mean = s * (1.0f / EMB);
  float var = s2 * (1.0f / EMB) - mean * mean;
  float inv = rsqrtf(var + 1e-5f);
#pragma unroll
  for (int i = 0; i < 4; ++i) {
    int c = tid + i * 256;
    out[(size_t)row * EMB + c] = (v[i] - mean) * inv * g[c] + bta[c];
  }
}

extern "C" void kernel_launch(void* const* d_in, const int* in_sizes, int n_in,
                              void* d_out, int out_size, void* d_ws, size_t ws_size,
                              hipStream_t stream) {
  const float* x = (const float*)d_in[0];
  const float* inW = (const float*)d_in[1];
  const float* inB = (const float*)d_in[2];
  const float* outW = (const float*)d_in[3];
  const float* opB = (const float*)d_in[4];
  const float* ggW = (const float*)d_in[5];
  const float* ggB = (const float*)d_in[6];
  const float* g1 = (const float*)d_in[7];
  const float* b1 = (const float*)d_in[8];
  const float* g2 = (const float*)d_in[9];
  const float* b2 = (const float*)d_in[10];
  float* out = (float*)d_out;
  char* ws = (char*)d_ws;
  const size_t MB = 1ull << 20;
  bf16* xb = (bf16*)(ws);              // 8 MB, dead after gemm_in
  bf16* hB = (bf16*)(ws);              // overlays xb (ln1 out)
  bf16* qr = (bf16*)(ws + 8 * MB);     // 8 MB, dead after gemm_in
  bf16* ctx = (bf16*)(ws + 8 * MB);    // overlays qr (attn output)
  bf16* wI = (bf16*)(ws + 16 * MB);    // 6 MB
  bf16* wO = (bf16*)(ws + 22 * MB);    // 2 MB
  bf16* wG = (bf16*)(ws + 24 * MB);    // 4 MB
  bf16* qb = (bf16*)(ws + 28 * MB);    // 8 MB, dead after attn
  bf16* kv = (bf16*)(ws + 36 * MB);    // 16 MB tile images, dead after attn
  bf16* projB = (bf16*)(ws + 28 * MB); // overlays qb+kv (GeGLU proj)
  float* ao = (float*)(ws + 52 * MB);  // 16 MB f32

  rope_cast<<<NTOK * 512 / 256, 256, 0, stream>>>(x, xb, qr);
  cast_all<<<6144, 256, 0, stream>>>(inW, outW, ggW, wI, wO, wG);
  gemm_in<<<dim3(24, 32), 256, 0, stream>>>(qr, xb, wI, inB, qb, kv);
  attn13<<<512, 256, 0, stream>>>(qb, kv, ctx);
  gemm_bt64<<<dim3(16, 32), 256, 0, stream>>>(ctx, wO, opB, ao,
                                              NTOK, 1024, 1024);
  ln1_k<<<NTOK, 256, 0, stream>>>(x, ao, g1, b1, ao, hB);
  gemm_bt<<<dim3(16, 32), 256, 0, stream>>>(hB, wG, ggB, nullptr, projB,
                                            NTOK, 2048, 1024);
  geglu_ln2<<<NTOK, 256, 0, stream>>>(ao, projB, g2, b2, out);
}

// Round 5
// 274.252 us; speedup vs baseline: 1.1017x; 1.0074x over previous
//
#include <hip/hip_runtime.h>

// TransformerBlock on MI355X (gfx950).
// v14: attention = dual-stream x counted-vmcnt. 256-thread blocks (4 waves x
// 32 q), 128-key tiles as TWO independent 64-key streams per iteration (PV of
// stream A overlaps S-MFMA of stream B in-wave; v10's +7pt MfmaUtil lever),
// double-buffered 2x32KB with raw s_barrier + counted s_waitcnt vmcnt(8)
// (loads in flight across barriers; v13's lever). Producer-swizzled K/V tile
// images, exp2, folded scales unchanged. Out-proj now uses the 128x128 GEMM;
// rope_cast+cast_all merged into one launch (7 launches total).

typedef __bf16 bf16;
typedef bf16 bf16x8 __attribute__((ext_vector_type(8)));
typedef bf16 bf16x4 __attribute__((ext_vector_type(4)));
typedef float f32x4 __attribute__((ext_vector_type(4)));
typedef float f32x16 __attribute__((ext_vector_type(16)));

#define EMB 1024
#define SEQ 2048
#define NTOK 4096
#define NH 16
#define HD 64

__device__ __forceinline__ f32x4 mfma16(bf16x8 a, bf16x8 b, f32x4 c) {
  return __builtin_amdgcn_mfma_f32_16x16x32_bf16(a, b, c, 0, 0, 0);
}
__device__ __forceinline__ f32x16 mfma32(bf16x8 a, bf16x8 b, f32x16 c) {
  return __builtin_amdgcn_mfma_f32_32x32x16_bf16(a, b, c, 0, 0, 0);
}

__device__ __forceinline__ void gll16(const void* g, void* l) {
  __builtin_amdgcn_global_load_lds(
      (const __attribute__((address_space(1))) void*)g,
      (__attribute__((address_space(3))) void*)l, 16, 0, 0);
}

__device__ __forceinline__ unsigned pk2(float a, float b) {
  union { bf16 h[2]; unsigned u; } t;
  t.h[0] = (bf16)a; t.h[1] = (bf16)b;
  return t.u;
}

// ---------------- fused elementwise prep (rope+cast, one launch) ----------
__global__ __launch_bounds__(256) void prep_all(
    const float* __restrict__ x, bf16* __restrict__ xb, bf16* __restrict__ qr,
    const float* __restrict__ w0, const float* __restrict__ w1,
    const float* __restrict__ w2, bf16* __restrict__ o0,
    bf16* __restrict__ o1, bf16* __restrict__ o2) {
  const int bid = blockIdx.x;
  if (bid < 8192) {
    // RoPE + cast of x (NTOK*512 work items)
    int idx = bid * 256 + threadIdx.x;
    int row = idx >> 9;
    int i = idx & 511;
    int h = i >> 5, d2 = i & 31;
    int pos = row & (SEQ - 1);
    int c0 = h * HD + d2;
    size_t base = (size_t)row * EMB;
    float x0 = x[base + c0], x1 = x[base + c0 + 32];
    float invf = exp2f(-(float)d2 * 0.4152410118609203f);
    float ang = (float)pos * invf;
    float sn, cs;
    sincosf(ang, &sn, &cs);
    qr[base + c0] = (bf16)(x0 * cs - x1 * sn);
    qr[base + c0 + 32] = (bf16)(x1 * cs + x0 * sn);
    xb[base + c0] = (bf16)x0;
    xb[base + c0 + 32] = (bf16)x1;
  } else {
    // weight casts: 6M floats total (3M + 1M + 2M)
    int i = ((bid - 8192) * 256 + threadIdx.x) * 4;
    const float* s; bf16* d; int off;
    if (i < 3 * 1024 * 1024) { s = w0; d = o0; off = i; }
    else if (i < 4 * 1024 * 1024) { s = w1; d = o1; off = i - 3 * 1024 * 1024; }
    else { s = w2; d = o2; off = i - 4 * 1024 * 1024; }
    float4 f = *(const float4*)(s + off);
    d[off] = (bf16)f.x; d[off + 1] = (bf16)f.y;
    d[off + 2] = (bf16)f.z; d[off + 3] = (bf16)f.w;
  }
}

// ---------------- fused in-proj GEMM ----------------
// Outputs: qb[token][1024] pre-scaled by 0.125; kv images per (b,h): 32 tiles
// of 64 keys, each {K 4096 elem | V 4096 elem} in the exact attention LDS
// layout. K pre-scaled by log2(e).
__global__ __launch_bounds__(256) void gemm_in(
    const bf16* __restrict__ Aq, const bf16* __restrict__ Ax,
    const bf16* __restrict__ W, const float* __restrict__ bias,
    bf16* __restrict__ qb, bf16* __restrict__ kv) {
  __shared__ bf16 As[128 * 32];
  __shared__ bf16 Bs[128 * 32];
  const int tid = threadIdx.x, lane = tid & 63, wave = tid >> 6;
  const int quad = lane >> 4, l16 = lane & 15;
  const int m0 = blockIdx.y * 128, n0 = blockIdx.x * 128;
  const bf16* A = (n0 < 2048) ? Aq : Ax;
  const int K = 1024;
  const int wm = (wave >> 1) * 64, wn = (wave & 1) * 64;
  const int srow = wave * 32 + (lane >> 2);
  const int scol = (lane & 3) * 8;
  f32x4 acc[4][4] = {};
  for (int k0 = 0; k0 < K; k0 += 32) {
    __syncthreads();
    gll16(A + (size_t)(m0 + srow) * K + k0 + scol, As + wave * 1024);
    gll16(A + (size_t)(m0 + srow + 16) * K + k0 + scol, As + wave * 1024 + 512);
    gll16(W + (size_t)(n0 + srow) * K + k0 + scol, Bs + wave * 1024);
    gll16(W + (size_t)(n0 + srow + 16) * K + k0 + scol, Bs + wave * 1024 + 512);
    __syncthreads();
    bf16x8 af[4], bw[4];
#pragma unroll
    for (int t = 0; t < 4; ++t) {
      af[t] = *(const bf16x8*)(As + (wm + t * 16 + l16) * 32 + quad * 8);
      bw[t] = *(const bf16x8*)(Bs + (wn + t * 16 + l16) * 32 + quad * 8);
    }
#pragma unroll
    for (int mt = 0; mt < 4; ++mt)
#pragma unroll
      for (int nt = 0; nt < 4; ++nt)
        acc[mt][nt] = mfma16(af[mt], bw[nt], acc[mt][nt]);
  }
  if (n0 < 1024) {
    // Q: scale 1/8 (exact in bf16)
#pragma unroll
    for (int mt = 0; mt < 4; ++mt)
      for (int nt = 0; nt < 4; ++nt) {
        const int n = n0 + wn + nt * 16 + l16;
        const float bv = bias[n];
#pragma unroll
        for (int r = 0; r < 4; ++r) {
          const int m = m0 + wm + mt * 16 + quad * 4 + r;
          qb[(size_t)m * 1024 + n] = (bf16)((acc[mt][nt][r] + bv) * 0.125f);
        }
      }
  } else if (n0 < 2048) {
    // K: scale log2(e), write into swizzled 64-key tile image
#pragma unroll
    for (int mt = 0; mt < 4; ++mt)
      for (int nt = 0; nt < 4; ++nt) {
        const int n = n0 + wn + nt * 16 + l16;
        const float bv = bias[n];
        const int kd = n - 1024, hh = kd >> 6, d = kd & 63;
        const int dc = d >> 3, dl = d & 7;
#pragma unroll
        for (int r = 0; r < 4; ++r) {
          const int m = m0 + wm + mt * 16 + quad * 4 + r;
          const int bb = m >> 11, s = m & 2047;
          const int t = s >> 6, kr = s & 63;
          const size_t base = ((size_t)((bb * 16 + hh) * 32 + t)) * 8192;
          kv[base + kr * 64 + ((dc ^ (kr & 7)) << 3) + dl] =
              (bf16)((acc[mt][nt][r] + bv) * 1.4426950408889634f);
        }
      }
  } else {
    // V: permuted+swizzled 64-key tile image, 4 tokens per bf16x4
#pragma unroll
    for (int mt = 0; mt < 4; ++mt)
      for (int nt = 0; nt < 4; ++nt) {
        const int n = n0 + wn + nt * 16 + l16;
        const float bv = bias[n];
        const int vd = n - 2048, hh = vd >> 6, d = vd & 63;
        const int m = m0 + wm + mt * 16 + quad * 4;
        const int bb = m >> 11, s = m & 2047;
        const int t = s >> 6, kt = s & 63;
        const int g = kt >> 4, w = kt & 15;
        const int c = 2 * g + ((w >> 2) & 1);
        const int slot = (w & 8) ? 4 : 0;
        const size_t base = ((size_t)((bb * 16 + hh) * 32 + t)) * 8192 + 4096;
        bf16x4 pkv;
#pragma unroll
        for (int r = 0; r < 4; ++r) pkv[r] = (bf16)(acc[mt][nt][r] + bv);
        *(bf16x4*)(kv + base + d * 64 + ((c ^ (d & 7)) << 3) + slot) = pkv;
      }
  }
}

// ---------------- GEMM 128x128: C = A @ W^T + bias ----------------
__global__ __launch_bounds__(256) void gemm_bt(
    const bf16* __restrict__ A, const bf16* __restrict__ W,
    const float* __restrict__ bias,
    float* __restrict__ outF, bf16* __restrict__ outB,
    int M, int N, int K) {
  __shared__ bf16 As[128 * 32];
  __shared__ bf16 Bs[128 * 32];
  const int tid = threadIdx.x, lane = tid & 63, wave = tid >> 6;
  const int quad = lane >> 4, l16 = lane & 15;
  const int m0 = blockIdx.y * 128, n0 = blockIdx.x * 128;
  const int wm = (wave >> 1) * 64, wn = (wave & 1) * 64;
  const int srow = wave * 32 + (lane >> 2);
  const int scol = (lane & 3) * 8;
  f32x4 acc[4][4] = {};
  for (int k0 = 0; k0 < K; k0 += 32) {
    __syncthreads();
    gll16(A + (size_t)(m0 + srow) * K + k0 + scol, As + wave * 1024);
    gll16(A + (size_t)(m0 + srow + 16) * K + k0 + scol, As + wave * 1024 + 512);
    gll16(W + (size_t)(n0 + srow) * K + k0 + scol, Bs + wave * 1024);
    gll16(W + (size_t)(n0 + srow + 16) * K + k0 + scol, Bs + wave * 1024 + 512);
    __syncthreads();
    bf16x8 af[4], bw[4];
#pragma unroll
    for (int t = 0; t < 4; ++t) {
      af[t] = *(const bf16x8*)(As + (wm + t * 16 + l16) * 32 + quad * 8);
      bw[t] = *(const bf16x8*)(Bs + (wn + t * 16 + l16) * 32 + quad * 8);
    }
#pragma unroll
    for (int mt = 0; mt < 4; ++mt)
#pragma unroll
      for (int nt = 0; nt < 4; ++nt)
        acc[mt][nt] = mfma16(af[mt], bw[nt], acc[mt][nt]);
  }
#pragma unroll
  for (int mt = 0; mt < 4; ++mt)
    for (int nt = 0; nt < 4; ++nt) {
      const int n = n0 + wn + nt * 16 + l16;
      const float bv = bias ? bias[n] : 0.0f;
#pragma unroll
      for (int r = 0; r < 4; ++r) {
        const int m = m0 + wm + mt * 16 + quad * 4 + r;
        const float v = acc[mt][nt][r] + bv;
        if (outF) outF[(size_t)m * N + n] = v;
        if (outB) outB[(size_t)m * N + n] = (bf16)v;
      }
    }
}

// ---------------- flash attention v14: dual-stream + counted vmcnt ---------
// 512 blocks x 256 threads (4 waves x 32 q). 16 iterations of 128-key tiles;
// each iteration runs two independent 64-key streams (ILP across S/exp/PV
// phases). Double-buffered 2x32KB; prefetch issued after a second barrier
// into the just-freed buffer; in-loop waits are vmcnt(8), never 0.
__global__ __launch_bounds__(256, 2) void attn14(
    const bf16* __restrict__ Q, const bf16* __restrict__ KV,
    bf16* __restrict__ ctx) {
  __shared__ __align__(16) bf16 kvb[2][16384];  // [buf][2 x (K 4096 | V 4096)]
  __shared__ float Linv[4][32];
  const int tid = threadIdx.x, lane = tid & 63, wave = tid >> 6;
  const int hi = lane >> 5, l31 = lane & 31, l7 = lane & 7;
  const int bid = blockIdx.x;
  const int hb = (bid & 7) * 4 + ((bid >> 3) & 3);
  const int qt = bid >> 5;              // 0..15
  const int h = hb & 15, b = hb >> 4;

  // Q B-frags (lane owns col q = l31; k=d=tt*16+hi*8+j), producer-scaled 1/8
  bf16x8 qf[4];
  {
    const int qrow = qt * 128 + wave * 32 + l31;
    const bf16* qp = Q + (size_t)(b * SEQ + qrow) * 1024 + h * HD + hi * 8;
#pragma unroll
    for (int t = 0; t < 4; ++t) qf[t] = *(const bf16x8*)(qp + t * 16);
  }
  // Drain Q loads so in-loop vmcnt counts track ONLY gll16 staging.
  asm volatile("s_waitcnt vmcnt(0)" ::: "memory");

  // staging: 16 x 128-key tiles (32KB each = 8 gll16/thread)
  const int soff = tid * 8;             // elements; = tid*16 bytes
  const bf16* kvg = KV + ((size_t)(b * NH + h) * 32) * 8192 + soff;
#pragma unroll
  for (int i = 0; i < 8; ++i)           // tile 0 -> buf 0
    gll16(kvg + i * 2048, kvb[0] + soff + i * 2048);
#pragma unroll
  for (int i = 0; i < 8; ++i)           // tile 1 -> buf 1
    gll16(kvg + 16384 + i * 2048, kvb[1] + soff + i * 2048);

  f32x16 o0 = {}, o1 = {};
  float lpart = 0.0f;
  const f32x16 zf = {};

  for (int t = 0; t < 16; ++t) {
    // tile t arrived (tile t+1's 8 loads stay in flight)
    if (t < 15) asm volatile("s_waitcnt vmcnt(8)" ::: "memory");
    else        asm volatile("s_waitcnt vmcnt(0)" ::: "memory");
    __builtin_amdgcn_s_barrier();
    __builtin_amdgcn_sched_barrier(0);
    const bf16* tb = kvb[t & 1];
    // two independent 64-key streams: phases interleave in-wave
#pragma unroll
    for (int half = 0; half < 2; ++half) {
      const bf16* ks = tb + half * 8192;
      const bf16* vs = ks + 4096;
      f32x16 s0, s1;
      __builtin_amdgcn_s_setprio(1);
      {
        const int swc = (hi ^ l7) * 8;
        bf16x8 k0 = *(const bf16x8*)(ks + l31 * 64 + swc);
        bf16x8 k1 = *(const bf16x8*)(ks + (32 + l31) * 64 + swc);
        s0 = mfma32(k0, qf[0], zf);     // zero-C: no per-tile re-zero movs
        s1 = mfma32(k1, qf[0], zf);
      }
#pragma unroll
      for (int tt = 1; tt < 4; ++tt) {
        const int swc = ((tt * 2 + hi) ^ l7) * 8;
        bf16x8 k0 = *(const bf16x8*)(ks + l31 * 64 + swc);
        bf16x8 k1 = *(const bf16x8*)(ks + (32 + l31) * 64 + swc);
        s0 = mfma32(k0, qf[tt], s0);
        s1 = mfma32(k1, qf[tt], s1);
      }
      __builtin_amdgcn_s_setprio(0);
      unsigned u[16];
#pragma unroll
      for (int g = 0; g < 8; ++g) {
        const int base = (g & 3) * 4;
        float e0, e1, e2, e3;
        if (g < 4) {
          e0 = __builtin_amdgcn_exp2f(s0[base]);
          e1 = __builtin_amdgcn_exp2f(s0[base + 1]);
          e2 = __builtin_amdgcn_exp2f(s0[base + 2]);
          e3 = __builtin_amdgcn_exp2f(s0[base + 3]);
        } else {
          e0 = __builtin_amdgcn_exp2f(s1[base]);
          e1 = __builtin_amdgcn_exp2f(s1[base + 1]);
          e2 = __builtin_amdgcn_exp2f(s1[base + 2]);
          e3 = __builtin_amdgcn_exp2f(s1[base + 3]);
        }
        lpart += (e0 + e1) + (e2 + e3);
        u[g * 2] = pk2(e0, e1);
        u[g * 2 + 1] = pk2(e2, e3);
      }
      // PV: chunk = (2kk + hi) ^ l7
      __builtin_amdgcn_s_setprio(1);
#pragma unroll
      for (int kk = 0; kk < 4; ++kk) {
        union { unsigned w[4]; bf16x8 v; } fw;
        fw.w[0] = u[4 * kk]; fw.w[1] = u[4 * kk + 1];
        fw.w[2] = u[4 * kk + 2]; fw.w[3] = u[4 * kk + 3];
        const int c16 = (2 * kk + hi) ^ l7;
        bf16x8 v0 = *(const bf16x8*)(vs + l31 * 64 + c16 * 8);
        bf16x8 v1 = *(const bf16x8*)(vs + (32 + l31) * 64 + c16 * 8);
        o0 = mfma32(fw.v, v0, o0);
        o1 = mfma32(fw.v, v1, o1);
      }
      __builtin_amdgcn_s_setprio(0);
    }
    // all waves done reading buf[t&1]; refill it with tile t+2
    __builtin_amdgcn_sched_barrier(0);
    __builtin_amdgcn_s_barrier();
    __builtin_amdgcn_sched_barrier(0);
    if (t + 2 < 16) {
      const bf16* src = kvg + (size_t)(t + 2) * 16384;
      bf16* dst = kvb[t & 1] + soff;
#pragma unroll
      for (int i = 0; i < 8; ++i) gll16(src + i * 2048, dst + i * 2048);
    }
  }
  // epilogue: lane (l31,hi) holds half the keys for q=l31; combine across hi
  float ltot = lpart + __shfl_xor(lpart, 32, 64);
  if (lane < 32) Linv[wave][lane] = 1.0f / ltot;
#pragma unroll
  for (int r = 0; r < 16; ++r) {
    const int qloc = (r & 3) + 8 * (r >> 2) + 4 * hi;
    const float inv = Linv[wave][qloc];
    const int qrow = qt * 128 + wave * 32 + qloc;
    bf16* cp = ctx + (size_t)(b * SEQ + qrow) * EMB + h * HD;
    cp[l31] = (bf16)(o0[r] * inv);
    cp[32 + l31] = (bf16)(o1[r] * inv);
  }
}

// ---------------- residual + LayerNorm ----------------
__global__ __launch_bounds__(256) void ln1_k(
    const float* __restrict__ x, const float* __restrict__ ao,
    const float* __restrict__ g, const float* __restrict__ bta,
    float* __restrict__ hF, bf16* __restrict__ hB) {
  int row = blockIdx.x, tid = threadIdx.x;
  const float* xr = x + (size_t)row * EMB;
  const float* ar = ao + (size_t)row * EMB;
  float v[4], s = 0.0f, s2 = 0.0f;
#pragma unroll
  for (int i = 0; i < 4; ++i) {
    float t = xr[tid + i * 256] + ar[tid + i * 256];
    v[i] = t; s += t; s2 += t * t;
  }
#pragma unroll
  for (int off = 1; off < 64; off <<= 1) {
    s += __shfl_xor(s, off, 64);
    s2 += __shfl_xor(s2, off, 64);
  }
  __shared__ float red[8];
  int wave = tid >> 6, lane = tid & 63;
  if (lane == 0) { red[wave] = s; red[4 + wave] = s2; }
  __syncthreads();
  s = red[0] + red[1] + red[2] + red[3];
  s2 = red[4] + red[5] + red[6] + red[7];
  float mean = s * (1.0f / EMB);
  float var = s2 * (1.0f / EMB) - mean * mean;
  float inv = rsqrtf(var + 1e-5f);
#pragma unroll
  for (int i = 0; i < 4; ++i) {
    int c = tid + i * 256;
    float t = (v[i] - mean) * inv * g[c] + bta[c];
    hF[(size_t)row * EMB + c] = t;
    hB[(size_t)row * EMB + c] = (bf16)t;
  }
}

__global__ __launch_bounds__(256) void geglu_ln2(
    const float* __restrict__ h, const bf16* __restrict__ proj,
    const float* __restrict__ g, const float* __restrict__ bta,
    float* __restrict__ out) {
  int row = blockIdx.x, tid = threadIdx.x;
  const float* hr = h + (size_t)row * EMB;
  const bf16* pr = proj + (size_t)row * 2048;
  float v[4], s = 0.0f, s2 = 0.0f;
#pragma unroll
  for (int i = 0; i < 4; ++i) {
    int c = tid + i * 256;
    float val = (float)pr[c];
    float gate = (float)pr[1024 + c];
    float ge = 0.5f * gate * (1.0f + erff(gate * 0.70710678f));
    float t = hr[c] + val * ge;
    v[i] = t; s += t; s2 += t * t;
  }
#pragma unroll
  for (int off = 1; off < 64; off <<= 1) {
    s += __shfl_xor(s, off, 64);
    s2 += __shfl_xor(s2, off, 64);
  }
  __shared__ float red[8];
  int wave = tid >> 6, lane = tid & 63;
  if (lane == 0) { red[wave] = s; red[4 + wave] = s2; }
  __syncthreads();
  s = red[0] + red[1] + red[2] + red[3];
  s2 = red[4] + red[5] + red[6] + red[7];
  float mean = s * (1.0f / EMB);
  float var = s2 * (1.0f / EMB) - mean * mean;
  float inv = rsqrtf(var + 1e-5f);
#pragma unroll
  for (int i = 0; i < 4; ++i) {
    int c = tid + i * 256;
    out[(size_t)row * EMB + c] = (v[i] - mean) * inv * g[c] + bta[c];
  }
}

extern "C" void kernel_launch(void* const* d_in, const int* in_sizes, int n_in,
                              void* d_out, int out_size, void* d_ws, size_t ws_size,
                              hipStream_t stream) {
  const float* x = (const float*)d_in[0];
  const float* inW = (const float*)d_in[1];
  const float* inB = (const float*)d_in[2];
  const float* outW = (const float*)d_in[3];
  const float* opB = (const float*)d_in[4];
  const float* ggW = (const float*)d_in[5];
  const float* ggB = (const float*)d_in[6];
  const float* g1 = (const float*)d_in[7];
  const float* b1 = (const float*)d_in[8];
  const float* g2 = (const float*)d_in[9];
  const float* b2 = (const float*)d_in[10];
  float* out = (float*)d_out;
  char* ws = (char*)d_ws;
  const size_t MB = 1ull << 20;
  bf16* xb = (bf16*)(ws);              // 8 MB, dead after gemm_in
  bf16* hB = (bf16*)(ws);              // overlays xb (ln1 out)
  bf16* qr = (bf16*)(ws + 8 * MB);     // 8 MB, dead after gemm_in
  bf16* ctx = (bf16*)(ws + 8 * MB);    // overlays qr (attn output)
  bf16* wI = (bf16*)(ws + 16 * MB);    // 6 MB
  bf16* wO = (bf16*)(ws + 22 * MB);    // 2 MB
  bf16* wG = (bf16*)(ws + 24 * MB);    // 4 MB
  bf16* qb = (bf16*)(ws + 28 * MB);    // 8 MB, dead after attn
  bf16* kv = (bf16*)(ws + 36 * MB);    // 16 MB tile images, dead after attn
  bf16* projB = (bf16*)(ws + 28 * MB); // overlays qb+kv (GeGLU proj)
  float* ao = (float*)(ws + 52 * MB);  // 16 MB f32

  prep_all<<<8192 + 6144, 256, 0, stream>>>(x, xb, qr, inW, outW, ggW,
                                            wI, wO, wG);
  gemm_in<<<dim3(24, 32), 256, 0, stream>>>(qr, xb, wI, inB, qb, kv);
  attn14<<<512, 256, 0, stream>>>(qb, kv, ctx);
  gemm_bt<<<dim3(8, 32), 256, 0, stream>>>(ctx, wO, opB, ao, nullptr,
                                           NTOK, 1024, 1024);
  ln1_k<<<NTOK, 256, 0, stream>>>(x, ao, g1, b1, ao, hB);
  gemm_bt<<<dim3(16, 32), 256, 0, stream>>>(hB, wG, ggB, nullptr, projB,
                                            NTOK, 2048, 1024);
  geglu_ln2<<<NTOK, 256, 0, stream>>>(ao, projB, g2, b2, out);
}

// Round 6
// 268.406 us; speedup vs baseline: 1.1257x; 1.0218x over previous
//
#include <hip/hip_runtime.h>

// TransformerBlock on MI355X (gfx950).
// v15: GEMM de-latency. All GEMMs (in-proj, out-proj, GeGLU) get the staging
// discipline proven in attn14: double-buffered LDS tiles, prefetch issued a
// full iteration ahead, counted s_waitcnt vmcnt(N) + raw s_barrier (the old
// __syncthreads drained vmcnt(0) every K-step, exposing full miss latency --
// gemm_in showed MfmaUtil 17 / VALU 11 / occ 14: latency-bound). Plus
// XCD-chunked block swizzle on all GEMM grids (FETCH was 72.8MB vs 22MB of
// inputs: L2 thrash). Out-proj back to 128x64 tiles (512 blocks = 2/CU).
// attn14 (dual-stream + counted vmcnt), prep_all, LNs unchanged.

typedef __bf16 bf16;
typedef bf16 bf16x8 __attribute__((ext_vector_type(8)));
typedef bf16 bf16x4 __attribute__((ext_vector_type(4)));
typedef float f32x4 __attribute__((ext_vector_type(4)));
typedef float f32x16 __attribute__((ext_vector_type(16)));

#define EMB 1024
#define SEQ 2048
#define NTOK 4096
#define NH 16
#define HD 64

__device__ __forceinline__ f32x4 mfma16(bf16x8 a, bf16x8 b, f32x4 c) {
  return __builtin_amdgcn_mfma_f32_16x16x32_bf16(a, b, c, 0, 0, 0);
}
__device__ __forceinline__ f32x16 mfma32(bf16x8 a, bf16x8 b, f32x16 c) {
  return __builtin_amdgcn_mfma_f32_32x32x16_bf16(a, b, c, 0, 0, 0);
}

__device__ __forceinline__ void gll16(const void* g, void* l) {
  __builtin_amdgcn_global_load_lds(
      (const __attribute__((address_space(1))) void*)g,
      (__attribute__((address_space(3))) void*)l, 16, 0, 0);
}

__device__ __forceinline__ unsigned pk2(float a, float b) {
  union { bf16 h[2]; unsigned u; } t;
  t.h[0] = (bf16)a; t.h[1] = (bf16)b;
  return t.u;
}

// XCD-chunked swizzle: linear block id -> (bx,by) such that each XCD's
// round-robin share is a contiguous chunk of the work space (L2 locality).
__device__ __forceinline__ void xcd_map(int nx, int nwg, int& bx, int& by) {
  const int lin = blockIdx.y * nx + blockIdx.x;
  const int id = (lin & 7) * (nwg >> 3) + (lin >> 3);  // nwg % 8 == 0
  bx = id % nx;
  by = id / nx;
}

// ---------------- fused elementwise prep (rope+cast, one launch) ----------
__global__ __launch_bounds__(256) void prep_all(
    const float* __restrict__ x, bf16* __restrict__ xb, bf16* __restrict__ qr,
    const float* __restrict__ w0, const float* __restrict__ w1,
    const float* __restrict__ w2, bf16* __restrict__ o0,
    bf16* __restrict__ o1, bf16* __restrict__ o2) {
  const int bid = blockIdx.x;
  if (bid < 8192) {
    int idx = bid * 256 + threadIdx.x;
    int row = idx >> 9;
    int i = idx & 511;
    int h = i >> 5, d2 = i & 31;
    int pos = row & (SEQ - 1);
    int c0 = h * HD + d2;
    size_t base = (size_t)row * EMB;
    float x0 = x[base + c0], x1 = x[base + c0 + 32];
    float invf = exp2f(-(float)d2 * 0.4152410118609203f);
    float ang = (float)pos * invf;
    float sn, cs;
    sincosf(ang, &sn, &cs);
    qr[base + c0] = (bf16)(x0 * cs - x1 * sn);
    qr[base + c0 + 32] = (bf16)(x1 * cs + x0 * sn);
    xb[base + c0] = (bf16)x0;
    xb[base + c0 + 32] = (bf16)x1;
  } else {
    int i = ((bid - 8192) * 256 + threadIdx.x) * 4;
    const float* s; bf16* d; int off;
    if (i < 3 * 1024 * 1024) { s = w0; d = o0; off = i; }
    else if (i < 4 * 1024 * 1024) { s = w1; d = o1; off = i - 3 * 1024 * 1024; }
    else { s = w2; d = o2; off = i - 4 * 1024 * 1024; }
    float4 f = *(const float4*)(s + off);
    d[off] = (bf16)f.x; d[off + 1] = (bf16)f.y;
    d[off + 2] = (bf16)f.z; d[off + 3] = (bf16)f.w;
  }
}

// ---------------- fused in-proj GEMM (double-buffered) ----------------
// Outputs: qb[token][1024] pre-scaled by 0.125; kv images per (b,h): 32 tiles
// of 64 keys, each {K 4096 elem | V 4096 elem} in the exact attention LDS
// layout. K pre-scaled by log2(e).
__global__ __launch_bounds__(256) void gemm_in(
    const bf16* __restrict__ Aq, const bf16* __restrict__ Ax,
    const bf16* __restrict__ W, const float* __restrict__ bias,
    bf16* __restrict__ qb, bf16* __restrict__ kv) {
  __shared__ bf16 As[2][4096];
  __shared__ bf16 Bs[2][4096];
  const int tid = threadIdx.x, lane = tid & 63, wave = tid >> 6;
  const int quad = lane >> 4, l16 = lane & 15;
  int bx, by;
  xcd_map(24, 24 * 32, bx, by);
  const int m0 = by * 128, n0 = bx * 128;
  const bf16* A = (n0 < 2048) ? Aq : Ax;
  const int K = 1024;
  const int wm = (wave >> 1) * 64, wn = (wave & 1) * 64;
  const int srow = wave * 32 + (lane >> 2);
  const int scol = (lane & 3) * 8;
  const bf16* a0 = A + (size_t)(m0 + srow) * K + scol;
  const bf16* a1 = A + (size_t)(m0 + srow + 16) * K + scol;
  const bf16* w0p = W + (size_t)(n0 + srow) * K + scol;
  const bf16* w1p = W + (size_t)(n0 + srow + 16) * K + scol;
  // prologue: tile 0 -> buf 0
  gll16(a0, As[0] + wave * 1024);
  gll16(a1, As[0] + wave * 1024 + 512);
  gll16(w0p, Bs[0] + wave * 1024);
  gll16(w1p, Bs[0] + wave * 1024 + 512);
  f32x4 acc[4][4] = {};
  for (int it = 0; it < 32; ++it) {
    const int cur = it & 1, nxt = cur ^ 1;
    if (it + 1 < 32) {                  // prefetch tile it+1
      const int k1 = (it + 1) * 32;
      gll16(a0 + k1, As[nxt] + wave * 1024);
      gll16(a1 + k1, As[nxt] + wave * 1024 + 512);
      gll16(w0p + k1, Bs[nxt] + wave * 1024);
      gll16(w1p + k1, Bs[nxt] + wave * 1024 + 512);
      asm volatile("s_waitcnt vmcnt(4)" ::: "memory");  // tile it arrived
    } else {
      asm volatile("s_waitcnt vmcnt(0)" ::: "memory");
    }
    __builtin_amdgcn_s_barrier();
    __builtin_amdgcn_sched_barrier(0);
    bf16x8 af[4], bw[4];
#pragma unroll
    for (int t = 0; t < 4; ++t) {
      af[t] = *(const bf16x8*)(As[cur] + (wm + t * 16 + l16) * 32 + quad * 8);
      bw[t] = *(const bf16x8*)(Bs[cur] + (wn + t * 16 + l16) * 32 + quad * 8);
    }
#pragma unroll
    for (int mt = 0; mt < 4; ++mt)
#pragma unroll
      for (int nt = 0; nt < 4; ++nt)
        acc[mt][nt] = mfma16(af[mt], bw[nt], acc[mt][nt]);
    __builtin_amdgcn_sched_barrier(0);
    __builtin_amdgcn_s_barrier();       // all reads of buf[cur] done
  }
  if (n0 < 1024) {
    // Q: scale 1/8 (exact in bf16)
#pragma unroll
    for (int mt = 0; mt < 4; ++mt)
      for (int nt = 0; nt < 4; ++nt) {
        const int n = n0 + wn + nt * 16 + l16;
        const float bv = bias[n];
#pragma unroll
        for (int r = 0; r < 4; ++r) {
          const int m = m0 + wm + mt * 16 + quad * 4 + r;
          qb[(size_t)m * 1024 + n] = (bf16)((acc[mt][nt][r] + bv) * 0.125f);
        }
      }
  } else if (n0 < 2048) {
    // K: scale log2(e), write into swizzled 64-key tile image
#pragma unroll
    for (int mt = 0; mt < 4; ++mt)
      for (int nt = 0; nt < 4; ++nt) {
        const int n = n0 + wn + nt * 16 + l16;
        const float bv = bias[n];
        const int kd = n - 1024, hh = kd >> 6, d = kd & 63;
        const int dc = d >> 3, dl = d & 7;
#pragma unroll
        for (int r = 0; r < 4; ++r) {
          const int m = m0 + wm + mt * 16 + quad * 4 + r;
          const int bb = m >> 11, s = m & 2047;
          const int t = s >> 6, kr = s & 63;
          const size_t base = ((size_t)((bb * 16 + hh) * 32 + t)) * 8192;
          kv[base + kr * 64 + ((dc ^ (kr & 7)) << 3) + dl] =
              (bf16)((acc[mt][nt][r] + bv) * 1.4426950408889634f);
        }
      }
  } else {
    // V: permuted+swizzled 64-key tile image, 4 tokens per bf16x4
#pragma unroll
    for (int mt = 0; mt < 4; ++mt)
      for (int nt = 0; nt < 4; ++nt) {
        const int n = n0 + wn + nt * 16 + l16;
        const float bv = bias[n];
        const int vd = n - 2048, hh = vd >> 6, d = vd & 63;
        const int m = m0 + wm + mt * 16 + quad * 4;
        const int bb = m >> 11, s = m & 2047;
        const int t = s >> 6, kt = s & 63;
        const int g = kt >> 4, w = kt & 15;
        const int c = 2 * g + ((w >> 2) & 1);
        const int slot = (w & 8) ? 4 : 0;
        const size_t base = ((size_t)((bb * 16 + hh) * 32 + t)) * 8192 + 4096;
        bf16x4 pkv;
#pragma unroll
        for (int r = 0; r < 4; ++r) pkv[r] = (bf16)(acc[mt][nt][r] + bv);
        *(bf16x4*)(kv + base + d * 64 + ((c ^ (d & 7)) << 3) + slot) = pkv;
      }
  }
}

// ---------------- GEMM 128x128: C = A @ W^T + bias (double-buffered) -------
__global__ __launch_bounds__(256) void gemm_bt(
    const bf16* __restrict__ A, const bf16* __restrict__ W,
    const float* __restrict__ bias,
    float* __restrict__ outF, bf16* __restrict__ outB,
    int M, int N, int K, int nbx) {
  __shared__ bf16 As[2][4096];
  __shared__ bf16 Bs[2][4096];
  const int tid = threadIdx.x, lane = tid & 63, wave = tid >> 6;
  const int quad = lane >> 4, l16 = lane & 15;
  int bx, by;
  xcd_map(nbx, nbx * 32, bx, by);
  const int m0 = by * 128, n0 = bx * 128;
  const int wm = (wave >> 1) * 64, wn = (wave & 1) * 64;
  const int srow = wave * 32 + (lane >> 2);
  const int scol = (lane & 3) * 8;
  const bf16* a0 = A + (size_t)(m0 + srow) * K + scol;
  const bf16* a1 = A + (size_t)(m0 + srow + 16) * K + scol;
  const bf16* w0p = W + (size_t)(n0 + srow) * K + scol;
  const bf16* w1p = W + (size_t)(n0 + srow + 16) * K + scol;
  gll16(a0, As[0] + wave * 1024);
  gll16(a1, As[0] + wave * 1024 + 512);
  gll16(w0p, Bs[0] + wave * 1024);
  gll16(w1p, Bs[0] + wave * 1024 + 512);
  f32x4 acc[4][4] = {};
  const int nit = K >> 5;
  for (int it = 0; it < nit; ++it) {
    const int cur = it & 1, nxt = cur ^ 1;
    if (it + 1 < nit) {
      const int k1 = (it + 1) * 32;
      gll16(a0 + k1, As[nxt] + wave * 1024);
      gll16(a1 + k1, As[nxt] + wave * 1024 + 512);
      gll16(w0p + k1, Bs[nxt] + wave * 1024);
      gll16(w1p + k1, Bs[nxt] + wave * 1024 + 512);
      asm volatile("s_waitcnt vmcnt(4)" ::: "memory");
    } else {
      asm volatile("s_waitcnt vmcnt(0)" ::: "memory");
    }
    __builtin_amdgcn_s_barrier();
    __builtin_amdgcn_sched_barrier(0);
    bf16x8 af[4], bw[4];
#pragma unroll
    for (int t = 0; t < 4; ++t) {
      af[t] = *(const bf16x8*)(As[cur] + (wm + t * 16 + l16) * 32 + quad * 8);
      bw[t] = *(const bf16x8*)(Bs[cur] + (wn + t * 16 + l16) * 32 + quad * 8);
    }
#pragma unroll
    for (int mt = 0; mt < 4; ++mt)
#pragma unroll
      for (int nt = 0; nt < 4; ++nt)
        acc[mt][nt] = mfma16(af[mt], bw[nt], acc[mt][nt]);
    __builtin_amdgcn_sched_barrier(0);
    __builtin_amdgcn_s_barrier();
  }
#pragma unroll
  for (int mt = 0; mt < 4; ++mt)
    for (int nt = 0; nt < 4; ++nt) {
      const int n = n0 + wn + nt * 16 + l16;
      const float bv = bias ? bias[n] : 0.0f;
#pragma unroll
      for (int r = 0; r < 4; ++r) {
        const int m = m0 + wm + mt * 16 + quad * 4 + r;
        const float v = acc[mt][nt][r] + bv;
        if (outF) outF[(size_t)m * N + n] = v;
        if (outB) outB[(size_t)m * N + n] = (bf16)v;
      }
    }
}

// ---------------- GEMM 128x64 tiles (double-buffered) ----------------
__global__ __launch_bounds__(256) void gemm_bt64(
    const bf16* __restrict__ A, const bf16* __restrict__ W,
    const float* __restrict__ bias, float* __restrict__ outF,
    int M, int N, int K) {
  __shared__ bf16 As[2][4096];
  __shared__ bf16 Bs[2][2048];
  const int tid = threadIdx.x, lane = tid & 63, wave = tid >> 6;
  const int quad = lane >> 4, l16 = lane & 15;
  int bx, by;
  xcd_map(16, 16 * 32, bx, by);
  const int m0 = by * 128, n0 = bx * 64;
  const int wm = (wave >> 1) * 64, wn = (wave & 1) * 32;
  const int srow = wave * 32 + (lane >> 2);
  const int srowB = wave * 16 + (lane >> 2);
  const int scol = (lane & 3) * 8;
  const bf16* a0 = A + (size_t)(m0 + srow) * K + scol;
  const bf16* a1 = A + (size_t)(m0 + srow + 16) * K + scol;
  const bf16* w0p = W + (size_t)(n0 + srowB) * K + scol;
  gll16(a0, As[0] + wave * 1024);
  gll16(a1, As[0] + wave * 1024 + 512);
  gll16(w0p, Bs[0] + wave * 512);
  f32x4 acc[4][2] = {};
  const int nit = K >> 5;
  for (int it = 0; it < nit; ++it) {
    const int cur = it & 1, nxt = cur ^ 1;
    if (it + 1 < nit) {
      const int k1 = (it + 1) * 32;
      gll16(a0 + k1, As[nxt] + wave * 1024);
      gll16(a1 + k1, As[nxt] + wave * 1024 + 512);
      gll16(w0p + k1, Bs[nxt] + wave * 512);
      asm volatile("s_waitcnt vmcnt(3)" ::: "memory");
    } else {
      asm volatile("s_waitcnt vmcnt(0)" ::: "memory");
    }
    __builtin_amdgcn_s_barrier();
    __builtin_amdgcn_sched_barrier(0);
    bf16x8 af[4], bw[2];
#pragma unroll
    for (int t = 0; t < 4; ++t)
      af[t] = *(const bf16x8*)(As[cur] + (wm + t * 16 + l16) * 32 + quad * 8);
#pragma unroll
    for (int t = 0; t < 2; ++t)
      bw[t] = *(const bf16x8*)(Bs[cur] + (wn + t * 16 + l16) * 32 + quad * 8);
#pragma unroll
    for (int mt = 0; mt < 4; ++mt)
#pragma unroll
      for (int nt = 0; nt < 2; ++nt)
        acc[mt][nt] = mfma16(af[mt], bw[nt], acc[mt][nt]);
    __builtin_amdgcn_sched_barrier(0);
    __builtin_amdgcn_s_barrier();
  }
#pragma unroll
  for (int mt = 0; mt < 4; ++mt)
    for (int nt = 0; nt < 2; ++nt) {
      const int n = n0 + wn + nt * 16 + l16;
      const float bv = bias[n];
#pragma unroll
      for (int r = 0; r < 4; ++r) {
        const int m = m0 + wm + mt * 16 + quad * 4 + r;
        outF[(size_t)m * N + n] = acc[mt][nt][r] + bv;
      }
    }
}

// ---------------- flash attention v14: dual-stream + counted vmcnt ---------
__global__ __launch_bounds__(256, 2) void attn14(
    const bf16* __restrict__ Q, const bf16* __restrict__ KV,
    bf16* __restrict__ ctx) {
  __shared__ __align__(16) bf16 kvb[2][16384];  // [buf][2 x (K 4096 | V 4096)]
  __shared__ float Linv[4][32];
  const int tid = threadIdx.x, lane = tid & 63, wave = tid >> 6;
  const int hi = lane >> 5, l31 = lane & 31, l7 = lane & 7;
  const int bid = blockIdx.x;
  const int hb = (bid & 7) * 4 + ((bid >> 3) & 3);
  const int qt = bid >> 5;              // 0..15
  const int h = hb & 15, b = hb >> 4;

  bf16x8 qf[4];
  {
    const int qrow = qt * 128 + wave * 32 + l31;
    const bf16* qp = Q + (size_t)(b * SEQ + qrow) * 1024 + h * HD + hi * 8;
#pragma unroll
    for (int t = 0; t < 4; ++t) qf[t] = *(const bf16x8*)(qp + t * 16);
  }
  asm volatile("s_waitcnt vmcnt(0)" ::: "memory");

  const int soff = tid * 8;
  const bf16* kvg = KV + ((size_t)(b * NH + h) * 32) * 8192 + soff;
#pragma unroll
  for (int i = 0; i < 8; ++i)
    gll16(kvg + i * 2048, kvb[0] + soff + i * 2048);
#pragma unroll
  for (int i = 0; i < 8; ++i)
    gll16(kvg + 16384 + i * 2048, kvb[1] + soff + i * 2048);

  f32x16 o0 = {}, o1 = {};
  float lpart = 0.0f;
  const f32x16 zf = {};

  for (int t = 0; t < 16; ++t) {
    if (t < 15) asm volatile("s_waitcnt vmcnt(8)" ::: "memory");
    else        asm volatile("s_waitcnt vmcnt(0)" ::: "memory");
    __builtin_amdgcn_s_barrier();
    __builtin_amdgcn_sched_barrier(0);
    const bf16* tb = kvb[t & 1];
#pragma unroll
    for (int half = 0; half < 2; ++half) {
      const bf16* ks = tb + half * 8192;
      const bf16* vs = ks + 4096;
      f32x16 s0, s1;
      __builtin_amdgcn_s_setprio(1);
      {
        const int swc = (hi ^ l7) * 8;
        bf16x8 k0 = *(const bf16x8*)(ks + l31 * 64 + swc);
        bf16x8 k1 = *(const bf16x8*)(ks + (32 + l31) * 64 + swc);
        s0 = mfma32(k0, qf[0], zf);
        s1 = mfma32(k1, qf[0], zf);
      }
#pragma unroll
      for (int tt = 1; tt < 4; ++tt) {
        const int swc = ((tt * 2 + hi) ^ l7) * 8;
        bf16x8 k0 = *(const bf16x8*)(ks + l31 * 64 + swc);
        bf16x8 k1 = *(const bf16x8*)(ks + (32 + l31) * 64 + swc);
        s0 = mfma32(k0, qf[tt], s0);
        s1 = mfma32(k1, qf[tt], s1);
      }
      __builtin_amdgcn_s_setprio(0);
      unsigned u[16];
#pragma unroll
      for (int g = 0; g < 8; ++g) {
        const int base = (g & 3) * 4;
        float e0, e1, e2, e3;
        if (g < 4) {
          e0 = __builtin_amdgcn_exp2f(s0[base]);
          e1 = __builtin_amdgcn_exp2f(s0[base + 1]);
          e2 = __builtin_amdgcn_exp2f(s0[base + 2]);
          e3 = __builtin_amdgcn_exp2f(s0[base + 3]);
        } else {
          e0 = __builtin_amdgcn_exp2f(s1[base]);
          e1 = __builtin_amdgcn_exp2f(s1[base + 1]);
          e2 = __builtin_amdgcn_exp2f(s1[base + 2]);
          e3 = __builtin_amdgcn_exp2f(s1[base + 3]);
        }
        lpart += (e0 + e1) + (e2 + e3);
        u[g * 2] = pk2(e0, e1);
        u[g * 2 + 1] = pk2(e2, e3);
      }
      __builtin_amdgcn_s_setprio(1);
#pragma unroll
      for (int kk = 0; kk < 4; ++kk) {
        union { unsigned w[4]; bf16x8 v; } fw;
        fw.w[0] = u[4 * kk]; fw.w[1] = u[4 * kk + 1];
        fw.w[2] = u[4 * kk + 2]; fw.w[3] = u[4 * kk + 3];
        const int c16 = (2 * kk + hi) ^ l7;
        bf16x8 v0 = *(const bf16x8*)(vs + l31 * 64 + c16 * 8);
        bf16x8 v1 = *(const bf16x8*)(vs + (32 + l31) * 64 + c16 * 8);
        o0 = mfma32(fw.v, v0, o0);
        o1 = mfma32(fw.v, v1, o1);
      }
      __builtin_amdgcn_s_setprio(0);
    }
    __builtin_amdgcn_sched_barrier(0);
    __builtin_amdgcn_s_barrier();
    __builtin_amdgcn_sched_barrier(0);
    if (t + 2 < 16) {
      const bf16* src = kvg + (size_t)(t + 2) * 16384;
      bf16* dst = kvb[t & 1] + soff;
#pragma unroll
      for (int i = 0; i < 8; ++i) gll16(src + i * 2048, dst + i * 2048);
    }
  }
  float ltot = lpart + __shfl_xor(lpart, 32, 64);
  if (lane < 32) Linv[wave][lane] = 1.0f / ltot;
#pragma unroll
  for (int r = 0; r < 16; ++r) {
    const int qloc = (r & 3) + 8 * (r >> 2) + 4 * hi;
    const float inv = Linv[wave][qloc];
    const int qrow = qt * 128 + wave * 32 + qloc;
    bf16* cp = ctx + (size_t)(b * SEQ + qrow) * EMB + h * HD;
    cp[l31] = (bf16)(o0[r] * inv);
    cp[32 + l31] = (bf16)(o1[r] * inv);
  }
}

// ---------------- residual + LayerNorm ----------------
__global__ __launch_bounds__(256) void ln1_k(
    const float* __restrict__ x, const float* __restrict__ ao,
    const float* __restrict__ g, const float* __restrict__ bta,
    float* __restrict__ hF, bf16* __restrict__ hB) {
  int row = blockIdx.x, tid = threadIdx.x;
  const float* xr = x + (size_t)row * EMB;
  const float* ar = ao + (size_t)row * EMB;
  float v[4], s = 0.0f, s2 = 0.0f;
#pragma unroll
  for (int i = 0; i < 4; ++i) {
    float t = xr[tid + i * 256] + ar[tid + i * 256];
    v[i] = t; s += t; s2 += t * t;
  }
#pragma unroll
  for (int off = 1; off < 64; off <<= 1) {
    s += __shfl_xor(s, off, 64);
    s2 += __shfl_xor(s2, off, 64);
  }
  __shared__ float red[8];
  int wave = tid >> 6, lane = tid & 63;
  if (lane == 0) { red[wave] = s; red[4 + wave] = s2; }
  __syncthreads();
  s = red[0] + red[1] + red[2] + red[3];
  s2 = red[4] + red[5] + red[6] + red[7];
  float mean = s * (1.0f / EMB);
  float var = s2 * (1.0f / EMB) - mean * mean;
  float inv = rsqrtf(var + 1e-5f);
#pragma unroll
  for (int i = 0; i < 4; ++i) {
    int c = tid + i * 256;
    float t = (v[i] - mean) * inv * g[c] + bta[c];
    hF[(size_t)row * EMB + c] = t;
    hB[(size_t)row * EMB + c] = (bf16)t;
  }
}

__global__ __launch_bounds__(256) void geglu_ln2(
    const float* __restrict__ h, const bf16* __restrict__ proj,
    const float* __restrict__ g, const float* __restrict__ bta,
    float* __restrict__ out) {
  int row = blockIdx.x, tid = threadIdx.x;
  const float* hr = h + (size_t)row * EMB;
  const bf16* pr = proj + (size_t)row * 2048;
  float v[4], s = 0.0f, s2 = 0.0f;
#pragma unroll
  for (int i = 0; i < 4; ++i) {
    int c = tid + i * 256;
    float val = (float)pr[c];
    float gate = (float)pr[1024 + c];
    float ge = 0.5f * gate * (1.0f + erff(gate * 0.70710678f));
    float t = hr[c] + val * ge;
    v[i] = t; s += t; s2 += t * t;
  }
#pragma unroll
  for (int off = 1; off < 64; off <<= 1) {
    s += __shfl_xor(s, off, 64);
    s2 += __shfl_xor(s2, off, 64);
  }
  __shared__ float red[8];
  int wave = tid >> 6, lane = tid & 63;
  if (lane == 0) { red[wave] = s; red[4 + wave] = s2; }
  __syncthreads();
  s = red[0] + red[1] + red[2] + red[3];
  s2 = red[4] + red[5] + red[6] + red[7];
  float mean = s * (1.0f / EMB);
  float var = s2 * (1.0f / EMB) - mean * mean;
  float inv = rsqrtf(var + 1e-5f);
#pragma unroll
  for (int i = 0; i < 4; ++i) {
    int c = tid + i * 256;
    out[(size_t)row * EMB + c] = (v[i] - mean) * inv * g[c] + bta[c];
  }
}

extern "C" void kernel_launch(void* const* d_in, const int* in_sizes, int n_in,
                              void* d_out, int out_size, void* d_ws, size_t ws_size,
                              hipStream_t stream) {
  const float* x = (const float*)d_in[0];
  const float* inW = (const float*)d_in[1];
  const float* inB = (const float*)d_in[2];
  const float* outW = (const float*)d_in[3];
  const float* opB = (const float*)d_in[4];
  const float* ggW = (const float*)d_in[5];
  const float* ggB = (const float*)d_in[6];
  const float* g1 = (const float*)d_in[7];
  const float* b1 = (const float*)d_in[8];
  const float* g2 = (const float*)d_in[9];
  const float* b2 = (const float*)d_in[10];
  float* out = (float*)d_out;
  char* ws = (char*)d_ws;
  const size_t MB = 1ull << 20;
  bf16* xb = (bf16*)(ws);              // 8 MB, dead after gemm_in
  bf16* hB = (bf16*)(ws);              // overlays xb (ln1 out)
  bf16* qr = (bf16*)(ws + 8 * MB);     // 8 MB, dead after gemm_in
  bf16* ctx = (bf16*)(ws + 8 * MB);    // overlays qr (attn output)
  bf16* wI = (bf16*)(ws + 16 * MB);    // 6 MB
  bf16* wO = (bf16*)(ws + 22 * MB);    // 2 MB
  bf16* wG = (bf16*)(ws + 24 * MB);    // 4 MB
  bf16* qb = (bf16*)(ws + 28 * MB);    // 8 MB, dead after attn
  bf16* kv = (bf16*)(ws + 36 * MB);    // 16 MB tile images, dead after attn
  bf16* projB = (bf16*)(ws + 28 * MB); // overlays qb+kv (GeGLU proj)
  float* ao = (float*)(ws + 52 * MB);  // 16 MB f32

  prep_all<<<8192 + 6144, 256, 0, stream>>>(x, xb, qr, inW, outW, ggW,
                                            wI, wO, wG);
  gemm_in<<<dim3(24, 32), 256, 0, stream>>>(qr, xb, wI, inB, qb, kv);
  attn14<<<512, 256, 0, stream>>>(qb, kv, ctx);
  gemm_bt64<<<dim3(16, 32), 256, 0, stream>>>(ctx, wO, opB, ao,
                                              NTOK, 1024, 1024);
  ln1_k<<<NTOK, 256, 0, stream>>>(x, ao, g1, b1, ao, hB);
  gemm_bt<<<dim3(16, 32), 256, 0, stream>>>(hB, wG, ggB, nullptr, projB,
                                            NTOK, 2048, 1024, 16);
  geglu_ln2<<<NTOK, 256, 0, stream>>>(ao, projB, g2, b2, out);
}